// Round 5
// baseline (624.933 us; speedup 1.0000x reference)
//
#include <hip/hip_runtime.h>
#include <hip/hip_bf16.h>

// ---------------- workspace layout (bytes) ----------------
#define AGG_OFF     0u          // f32[4096*50]  (zeroed)
#define DEG_OFF     819200u     // f32[4096]     (zeroed)
#define XP_OFF      835584u     // f32[64]       (zeroed)
#define HIST_OFF    835840u     // u32[257]      (zeroed)
#define SCAL_OFF    836992u     // i32[8]        (zeroed; written by scan)
#define S_OFF       837120u     // f32[50] colsum of h
#define H_OFF       1048576u    // f32[4096][50] row-major
#define HT_OFF      1867776u    // f32[50][4096] transposed
#define SQ_OFF      2686976u    // f32[4096] row squared-norms
#define W2H_OFF     2703360u    // u16[64][640] bf16-hi of w2 (padded, transposed)
#define W2L_OFF     2785280u    // u16[64][640] bf16-lo

typedef __attribute__((ext_vector_type(8))) short short8;
typedef __attribute__((ext_vector_type(4))) float f32x4;

__device__ __forceinline__ unsigned short f32_to_bf16_rne(float v) {
    unsigned u = __float_as_uint(v);
    unsigned r = u + 0x7FFFu + ((u >> 16) & 1u);
    return (unsigned short)(r >> 16);
}
__device__ __forceinline__ float bf16_to_f32(unsigned short s) {
    return __uint_as_float(((unsigned)s) << 16);
}

// ============================================================
// Kernel 0: zero the accumulator region of the workspace
// ============================================================
__global__ __launch_bounds__(256) void mil_init(unsigned int* __restrict__ w)
{
    w[(size_t)blockIdx.x * 256u + threadIdx.x] = 0u;
}

// ============================================================
// Kernel 0b: split w2 -> bf16 hi/lo planes, transposed [c][k],
// K = (ci,ky,kx) flattened = w2's native inner order; pad c->64, k->640
// ============================================================
__global__ __launch_bounds__(256) void mil_wprep(
    const float* __restrict__ w2, unsigned short* __restrict__ w2h,
    unsigned short* __restrict__ w2l)
{
    const int gid = blockIdx.x * 256 + threadIdx.x;   // < 40960 = 64*640
    const int k = gid % 640;
    const int c = gid / 640;
    const float v = (c < 50 && k < 500) ? w2[c*500 + k] : 0.f;
    const unsigned short h = f32_to_bf16_rne(v);
    const unsigned short l = f32_to_bf16_rne(v - bf16_to_f32(h));
    w2h[gid] = h;
    w2l[gid] = l;
}

// ============================================================
// Kernel 1: per-instance LeNet -> h[4096][50], hT[50][4096], sq[4096]
// conv2 as split-bf16 MFMA implicit GEMM (3-product: hi*hi+hi*lo+lo*hi,
// ~6e-6 rel err). A-frags built in-registers from pool1 via offset table.
// ============================================================
__global__ __launch_bounds__(256, 3) void mil_cnn(
    const float* __restrict__ x, const float* __restrict__ w1, const float* __restrict__ b1,
    const unsigned short* __restrict__ w2h, const unsigned short* __restrict__ w2l,
    const float* __restrict__ b2,
    const float* __restrict__ fcw, const float* __restrict__ fcb,
    float* __restrict__ hout, float* __restrict__ hT, float* __restrict__ sqout)
{
    __shared__ __align__(16) float img[784];
    __shared__ float w1s[500];
    __shared__ float b1s[20];
    __shared__ float b2s[50];
    __shared__ __align__(16) float pool1[20*144];
    __shared__ __align__(16) float pool2[800];
    __shared__ float hloc[50];
    __shared__ int tabk[640];

    const int n = blockIdx.x;
    const int t = threadIdx.x;

    const float* xin = x + (size_t)n * 784;
    for (int i = t; i < 784; i += 256) img[i] = xin[i];
    for (int i = t; i < 500; i += 256) w1s[i] = w1[i];
    if (t < 20) b1s[t] = b1[t];
    { int u = t - 32; if (u >= 0 && u < 50) b2s[u] = b2[u]; }
    // k -> pool1 offset table (k = ci*25 + ky*5 + kx; -1 for pad)
    for (int kidx = t; kidx < 640; kidx += 256) {
        int off = -1;
        if (kidx < 500) {
            const int ci = kidx / 25, r = kidx % 25;
            off = ci*144 + (r/5)*12 + (r%5);
        }
        tabk[kidx] = off;
    }
    __syncthreads();

    // ---- conv1 (5x5, 1->20) + relu + 2x2 maxpool -> pool1[20][12][12]
    if (t < 240) {
        const int c = t / 12, py = t % 12;
        float wr[25];
#pragma unroll
        for (int k = 0; k < 25; k++) wr[k] = w1s[c*25 + k];
        float acc0[24], acc1[24];
#pragma unroll
        for (int i = 0; i < 24; i++) { acc0[i] = 0.f; acc1[i] = 0.f; }
#pragma unroll
        for (int ky = 0; ky < 5; ky++) {
            const int yr = 2*py + ky;
            float ra[28], rb[28];
#pragma unroll
            for (int i = 0; i < 28; i++) ra[i] = img[yr*28 + i];
#pragma unroll
            for (int i = 0; i < 28; i++) rb[i] = img[yr*28 + 28 + i];
#pragma unroll
            for (int kx = 0; kx < 5; kx++) {
                const float wv = wr[ky*5 + kx];
#pragma unroll
                for (int xo = 0; xo < 24; xo++) {
                    acc0[xo] = fmaf(ra[xo+kx], wv, acc0[xo]);
                    acc1[xo] = fmaf(rb[xo+kx], wv, acc1[xo]);
                }
            }
        }
        const float bias = b1s[c];
#pragma unroll
        for (int px = 0; px < 12; px++) {
            float v = fmaxf(fmaxf(acc0[2*px], acc0[2*px+1]),
                            fmaxf(acc1[2*px], acc1[2*px+1]));
            pool1[c*144 + py*12 + px] = fmaxf(v + bias, 0.f);
        }
    }
    __syncthreads();

    // ---- conv2: D[s=64][c=64] = A[s][K=640] * W[K][c], MFMA 16x16x32 bf16
    {
        const int lane = t & 63, wv = t >> 6;        // wave wv owns spatial rows 16wv..16wv+15
        const int cL = lane & 15, g = lane >> 4;
        const int srow = wv*16 + cL;                 // A-frag row (spatial)
        const int soff = (srow >> 3)*12 + (srow & 7);// oy*12 + ox
        f32x4 acc[4];
#pragma unroll
        for (int nn = 0; nn < 4; ++nn) acc[nn] = (f32x4){0.f, 0.f, 0.f, 0.f};

        for (int kk = 0; kk < 20; ++kk) {
            const int k0 = kk*32 + g*8;
            short8 ah, al;
#pragma unroll
            for (int e = 0; e < 8; ++e) {
                const int off = tabk[k0 + e];
                const float v = (off >= 0) ? pool1[off + soff] : 0.f;
                const unsigned short hh = f32_to_bf16_rne(v);
                const unsigned short ll = f32_to_bf16_rne(v - bf16_to_f32(hh));
                ah[e] = (short)hh;
                al[e] = (short)ll;
            }
#pragma unroll
            for (int nn = 0; nn < 4; ++nn) {
                const int bo = (nn*16 + cL)*640 + k0;
                const short8 bh = *(const short8*)(w2h + bo);
                const short8 bl = *(const short8*)(w2l + bo);
                acc[nn] = __builtin_amdgcn_mfma_f32_16x16x32_bf16(al, bh, acc[nn], 0, 0, 0);
                acc[nn] = __builtin_amdgcn_mfma_f32_16x16x32_bf16(ah, bl, acc[nn], 0, 0, 0);
                acc[nn] = __builtin_amdgcn_mfma_f32_16x16x32_bf16(ah, bh, acc[nn], 0, 0, 0);
            }
        }
        // epilogue: 2x2 maxpool + bias + relu -> pool2[c*16 + py*4 + px]
        // D layout: col=lane&15, row=(lane>>4)*4+reg; wave wv holds s=16wv..16wv+15
        // => pool row py = wv; x-pairs = adjacent regs; y-pair = lane^32
#pragma unroll
        for (int nn = 0; nn < 4; ++nn) {
            const float x0 = fmaxf(acc[nn].x, acc[nn].y);
            const float x1 = fmaxf(acc[nn].z, acc[nn].w);
            const float y0 = fmaxf(x0, __shfl_xor(x0, 32));
            const float y1 = fmaxf(x1, __shfl_xor(x1, 32));
            if (lane < 32) {
                const int c = nn*16 + cL;
                if (c < 50) {
                    const float bias = b2s[c];
                    pool2[c*16 + wv*4 + 2*g + 0] = fmaxf(y0 + bias, 0.f);
                    pool2[c*16 + wv*4 + 2*g + 1] = fmaxf(y1 + bias, 0.f);
                }
            }
        }
    }
    __syncthreads();

    // ---- fc: h[o] = relu(sum_k fcw[o][k]*pool2[k] + fcb[o]); one wave per o-slice
    {
        const int wv = t >> 6, lane = t & 63;
        for (int o = wv; o < 50; o += 4) {
            float acc = 0.f;
#pragma unroll
            for (int r = 0; r < 13; r++) {
                const int k = r*64 + lane;
                if (k < 800) acc = fmaf(fcw[o*800 + k], pool2[k], acc);
            }
#pragma unroll
            for (int off = 32; off > 0; off >>= 1) acc += __shfl_xor(acc, off);
            if (lane == 0) hloc[o] = fmaxf(acc + fcb[o], 0.f);
        }
    }
    __syncthreads();
    if (t < 50) {
        const float v = hloc[t];
        hout[(size_t)n*50 + t] = v;
        hT[(size_t)t*4096 + n] = v;
    }
    if (t < 64) {
        float s = (t < 50) ? hloc[t]*hloc[t] : 0.f;
#pragma unroll
        for (int off = 32; off > 0; off >>= 1) s += __shfl_xor(s, off);
        if (t == 0) sqout[n] = s;
    }
}

// ============================================================
// Kernel 1b: S[d] = sum_n h[n][d]  (reads hT rows, coalesced)
// ============================================================
__global__ __launch_bounds__(256) void mil_colsum(
    const float* __restrict__ hT, float* __restrict__ S)
{
    __shared__ float red[4];
    const int d = blockIdx.x, t = threadIdx.x;
    float s = 0.f;
    for (int nn = t; nn < 4096; nn += 256) s += hT[(size_t)d*4096 + nn];
#pragma unroll
    for (int off = 32; off > 0; off >>= 1) s += __shfl_xor(s, off);
    if ((t & 63) == 0) red[t >> 6] = s;
    __syncthreads();
    if (t == 0) S[d] = red[0] + red[1] + red[2] + red[3];
}

// ============================================================
// Kernel 2: pairwise distances -> cumulative-histogram buckets.
// 128x128 tile, 8x8/thread; wave-aggregated LDS histogram atomics.
// ============================================================
__global__ __launch_bounds__(256, 3) void mil_hist(
    const float* __restrict__ hT, const float* __restrict__ sq,
    unsigned int* __restrict__ hist)
{
    __shared__ __align__(16) float hiT[6400];   // [50][128]
    __shared__ __align__(16) float hjT[6400];
    __shared__ float sqi[128], sqj[128];
    __shared__ unsigned int lh[257];

    const int t = threadIdx.x;
    const int lane = t & 63;
    const int i0 = blockIdx.x * 128, j0 = blockIdx.y * 128;

    for (int idx = t; idx < 6400; idx += 256) {
        const int c = idx >> 7, l = idx & 127;
        hiT[idx] = hT[(size_t)c*4096 + i0 + l];
        hjT[idx] = hT[(size_t)c*4096 + j0 + l];
    }
    if (t < 128) { sqi[t] = sq[i0 + t]; sqj[t] = sq[j0 + t]; }
    for (int idx = t; idx < 257; idx += 256) lh[idx] = 0;
    __syncthreads();

    const int ti = t >> 4, tj = t & 15;
    float acc[8][8];
#pragma unroll
    for (int a = 0; a < 8; a++)
#pragma unroll
        for (int b = 0; b < 8; b++) acc[a][b] = 0.f;

    for (int c = 0; c < 50; c++) {
        const float4 a0 = *(const float4*)&hiT[c*128 + ti*8];
        const float4 a1 = *(const float4*)&hiT[c*128 + ti*8 + 4];
        const float4 b0 = *(const float4*)&hjT[c*128 + tj*8];
        const float4 b1 = *(const float4*)&hjT[c*128 + tj*8 + 4];
        const float aa[8] = {a0.x,a0.y,a0.z,a0.w,a1.x,a1.y,a1.z,a1.w};
        const float bb[8] = {b0.x,b0.y,b0.z,b0.w,b1.x,b1.y,b1.z,b1.w};
#pragma unroll
        for (int a = 0; a < 8; a++)
#pragma unroll
            for (int b = 0; b < 8; b++)
                acc[a][b] = fmaf(aa[a], bb[b], acc[a][b]);
    }

#pragma unroll
    for (int a = 0; a < 8; a++) {
#pragma unroll
        for (int b = 0; b < 8; b++) {
            const int gi = i0 + ti*8 + a, gj = j0 + tj*8 + b;
            int kb = -1;
            if (gi != gj) {
                const float d2 = sqi[ti*8+a] + sqj[tj*8+b] - 2.f*acc[a][b];
                const float d = sqrtf(fmaxf(d2, 0.f));
                int k = (int)floorf((d - 3.5f)*2.f) + 1;
                k = k < 0 ? 0 : (k > 256 ? 256 : k);
                if (k > 0   && d <  3.5f + 0.5f*(float)(k-1)) k--;
                if (k < 256 && d >= 3.5f + 0.5f*(float)k)     k++;
                kb = k;
            }
            // wave-aggregated histogram update
            unsigned long long act = __ballot(kb >= 0);
            while (act) {
                const int src = __ffsll(act) - 1;
                const int kk = __shfl(kb, src);
                const unsigned long long same = __ballot(kb == kk) & act;
                if (lane == src) atomicAdd(&lh[kk], (unsigned)__popcll(same));
                act &= ~same;
            }
        }
    }
    __syncthreads();
    for (int idx = t; idx < 257; idx += 256)
        if (lh[idx]) atomicAdd(&hist[idx], lh[idx]);
}

// ============================================================
// Kernel 3: prefix-scan histogram -> kc, nnz, complement flag
// ============================================================
__global__ void mil_scan(const unsigned int* __restrict__ hist, int* __restrict__ scal)
{
    if (threadIdx.x == 0) {
        unsigned long long cum = 0, nz = 0;
        int kc = -1;
        for (int k = 0; k < 256; k++) {
            cum += hist[k];
            if (kc < 0 && cum >= 410ull) { kc = k; nz = cum; }  // ceil(0.1*4096)
        }
        if (kc < 0) { kc = 0; nz = hist[0]; }
        scal[0] = kc;
        scal[1] = (int)nz;
        scal[2] = (nz * 2ull > 16773120ull) ? 1 : 0;   // complement mode if >half dense
    }
}

// ============================================================
// Kernel 4: recompute distances (identical FMA chain to round-3 agg),
// accumulate mask (or complement when inv): agg/deg of the chosen set.
// ============================================================
__global__ __launch_bounds__(256, 3) void mil_agg(
    const float* __restrict__ h, const float* __restrict__ hT, const float* __restrict__ sq,
    const int* __restrict__ scal, float* __restrict__ agg, float* __restrict__ deg)
{
    __shared__ __align__(16) float hiT[3200];       // [50][64]
    __shared__ __align__(16) float hjT[3200];
    __shared__ float sqi[64], sqj[64];
    __shared__ __align__(16) float hsub[4096];      // [jj][d], d padded to 64
    __shared__ __align__(16) unsigned char mk[4096];// mask, transposed: [jj][il]

    const int t = threadIdx.x;
    const int i0 = blockIdx.x * 64;
    const float thr = 3.5f + 0.5f * (float)scal[0]; // exact in f32
    const bool inv = (scal[2] != 0);

    for (int idx = t; idx < 3200; idx += 256) {
        const int c = idx >> 6, l = idx & 63;
        hiT[idx] = hT[(size_t)c*4096 + i0 + l];
    }
    if (t < 64) sqi[t] = sq[i0 + t];

    const int ti = t >> 4, tj = t & 15;   // gram layout
    const int il = t >> 2, dq = t & 3;    // aggregate layout
    float accum[16];
#pragma unroll
    for (int i = 0; i < 16; i++) accum[i] = 0.f;
    int degc = 0;

    for (int js = 0; js < 8; js++) {
        const int j0 = blockIdx.y * 512 + js * 64;
        __syncthreads();
        for (int idx = t; idx < 3200; idx += 256) {
            const int c = idx >> 6, l = idx & 63;
            hjT[idx] = hT[(size_t)c*4096 + j0 + l];
        }
        for (int idx = t; idx < 4096; idx += 256) {
            const int jj = idx >> 6, d = idx & 63;
            hsub[idx] = (d < 50) ? h[(size_t)(j0 + jj)*50 + d] : 0.f;
        }
        if (t < 64) sqj[t] = sq[j0 + t];
        __syncthreads();

        float acc[4][4];
#pragma unroll
        for (int a = 0; a < 4; a++)
#pragma unroll
            for (int b = 0; b < 4; b++) acc[a][b] = 0.f;
        for (int c = 0; c < 50; c++) {
            const float4 av = *(const float4*)&hiT[c*64 + ti*4];
            const float4 bv = *(const float4*)&hjT[c*64 + tj*4];
            const float aa[4] = {av.x, av.y, av.z, av.w};
            const float bb[4] = {bv.x, bv.y, bv.z, bv.w};
#pragma unroll
            for (int a = 0; a < 4; a++)
#pragma unroll
                for (int b = 0; b < 4; b++)
                    acc[a][b] = fmaf(aa[a], bb[b], acc[a][b]);
        }

#pragma unroll
        for (int b = 0; b < 4; b++) {
            unsigned char ob[4];
#pragma unroll
            for (int a = 0; a < 4; a++) {
                const int gi = i0 + ti*4 + a, gj = j0 + tj*4 + b;
                const float d2 = sqi[ti*4+a] + sqj[tj*4+b] - 2.f*acc[a][b];
                const float dd = sqrtf(fmaxf(d2, 0.f));
                const bool edge = (dd < thr);
                ob[a] = (gi != gj && (edge != inv)) ? 1 : 0;
            }
            *(uchar4*)&mk[(tj*4+b)*64 + ti*4] = make_uchar4(ob[0], ob[1], ob[2], ob[3]);
        }
        __syncthreads();

        for (int jj = 0; jj < 64; jj++) {
            const bool e = (mk[jj*64 + il] != 0);
            if (!__any(e)) continue;          // fast path: whole-wave skip
            const float m = e ? 1.f : 0.f;
            if (e && dq == 0) degc++;
#pragma unroll
            for (int q = 0; q < 4; q++) {
                const float4 hv = *(const float4*)&hsub[jj*64 + dq*16 + q*4];
                accum[q*4+0] = fmaf(m, hv.x, accum[q*4+0]);
                accum[q*4+1] = fmaf(m, hv.y, accum[q*4+1]);
                accum[q*4+2] = fmaf(m, hv.z, accum[q*4+2]);
                accum[q*4+3] = fmaf(m, hv.w, accum[q*4+3]);
            }
        }
    }

    const int node = i0 + il;
#pragma unroll
    for (int q = 0; q < 4; q++)
#pragma unroll
        for (int rr = 0; rr < 4; rr++) {
            const int d = dq*16 + q*4 + rr;
            if (d < 50 && accum[q*4+rr] != 0.f)
                atomicAdd(&agg[(size_t)node*50 + d], accum[q*4+rr]);
        }
    if (dq == 0 && degc) atomicAdd(&deg[node], (float)degc);
}

// ============================================================
// Kernel 5: Z = leaky(mean-agg@relW^T + relb + h@rootW^T); Xp += colsum(Z)
// Complement correction: agg_true = S - h[i] - comp; deg_true = 4095 - compdeg
// ============================================================
__global__ __launch_bounds__(256) void mil_sage(
    const float* __restrict__ h, const float* __restrict__ agg, const float* __restrict__ deg,
    const float* __restrict__ S, const int* __restrict__ scal,
    const float* __restrict__ relw, const float* __restrict__ relb,
    const float* __restrict__ rootw, float* __restrict__ Xp)
{
    __shared__ float relT[2500];   // [c][d]
    __shared__ float rootT[2500];
    __shared__ float rb[50];
    __shared__ float hn[250], mn[250], zb[250];
    const int t = threadIdx.x;
    const int nb = blockIdx.x * 5;
    const bool inv = (scal[2] != 0);

    for (int idx = t; idx < 2500; idx += 256) {
        const int d = idx / 50, c = idx % 50;
        relT[c*50 + d]  = relw[idx];
        rootT[c*50 + d] = rootw[idx];
    }
    if (t < 50) rb[t] = relb[t];
    if (t < 250) {
        const int nl = t / 50, d = t % 50;
        const int node = nb + nl;
        if (node < 4096) {
            const float hv = h[(size_t)node*50 + d];
            float av = agg[(size_t)node*50 + d];
            float dg = deg[node];
            if (inv) { av = S[d] - hv - av; dg = 4095.f - dg; }
            hn[t] = hv;
            mn[t] = av / fmaxf(dg, 1.f);
        } else { hn[t] = 0.f; mn[t] = 0.f; }
    }
    __syncthreads();
    if (t < 250) {
        const int nl = t / 50, d = t % 50;
        float z = rb[d];
        for (int c = 0; c < 50; c++) {
            z = fmaf(mn[nl*50 + c], relT[c*50 + d], z);
            z = fmaf(hn[nl*50 + c], rootT[c*50 + d], z);
        }
        z = z > 0.f ? z : 0.01f * z;
        zb[t] = (nb + nl < 4096) ? z : 0.f;
    }
    __syncthreads();
    if (t < 50) {
        float s = 0.f;
#pragma unroll
        for (int nl = 0; nl < 5; nl++) s += zb[nl*50 + t];
        atomicAdd(&Xp[t], s);
    }
}

// ============================================================
// Kernel 6: pooled sage + lin1 + lin2 + softmax -> out[3] (f32)
// ============================================================
__global__ void mil_final(
    const float* __restrict__ Xp, const int* __restrict__ scal,
    const float* __restrict__ relw, const float* __restrict__ relb,
    const float* __restrict__ rootw,
    const float* __restrict__ l1w, const float* __restrict__ l1b,
    const float* __restrict__ l2w, const float* __restrict__ l2b,
    float* __restrict__ out)
{
    __shared__ float xp[50], x2[50], v1[25], v2[2];
    const int t = threadIdx.x;
    if (t < 50) xp[t] = Xp[t];
    __syncthreads();
    const float adjp = (float)scal[1];
    const float dmax = fmaxf(adjp, 1.f);
    if (t < 50) {
        float z = relb[t];
        for (int c = 0; c < 50; c++) {
            const float mnc = (adjp * xp[c]) / dmax;
            z = fmaf(mnc,   relw[t*50 + c], z);
            z = fmaf(xp[c], rootw[t*50 + c], z);
        }
        x2[t] = z > 0.f ? z : 0.01f*z;
    }
    __syncthreads();
    if (t < 25) {
        float v = l1b[t];
        for (int c = 0; c < 50; c++) v = fmaf(l1w[t*50 + c], x2[c], v);
        v1[t] = v > 0.f ? v : 0.01f*v;
    }
    __syncthreads();
    if (t < 2) {
        float v = l2b[t];
        for (int c = 0; c < 25; c++) v = fmaf(l2w[t*25 + c], v1[c], v);
        v2[t] = v > 0.f ? v : 0.01f*v;
    }
    __syncthreads();
    if (t == 0) {
        const float a = v2[0], b = v2[1];
        const float mx = fmaxf(a, b);
        const float e0 = expf(a - mx), e1 = expf(b - mx);
        const float s = e0 + e1;
        const float p0 = e0 / s, p1 = e1 / s;
        const float pm = fmaxf(p0, p1);
        const float am = (p1 > p0) ? 1.f : 0.f;
        const int nnz = scal[1];
        const float l1v = sqrtf((float)(16777216 - nnz)) / 16777216.f;
        out[0] = pm;
        out[1] = am;
        out[2] = l1v;
    }
}

// ============================================================
extern "C" void kernel_launch(void* const* d_in, const int* in_sizes, int n_in,
                              void* d_out, int out_size, void* d_ws, size_t ws_size,
                              hipStream_t stream)
{
    (void)in_sizes; (void)n_in; (void)out_size; (void)ws_size;
    const float* x     = (const float*)d_in[0];
    const float* w1    = (const float*)d_in[1];
    const float* b1    = (const float*)d_in[2];
    const float* w2    = (const float*)d_in[3];
    const float* b2    = (const float*)d_in[4];
    const float* fcw   = (const float*)d_in[5];
    const float* fcb   = (const float*)d_in[6];
    const float* relw  = (const float*)d_in[7];
    const float* relb  = (const float*)d_in[8];
    const float* rootw = (const float*)d_in[9];
    // d_in[10..14] (pool_*, mlp_*) are dead: softmax over a length-1 axis == 1
    const float* l1w   = (const float*)d_in[15];
    const float* l1b   = (const float*)d_in[16];
    const float* l2w   = (const float*)d_in[17];
    const float* l2b   = (const float*)d_in[18];

    char* ws = (char*)d_ws;
    float* agg = (float*)(ws + AGG_OFF);
    float* deg = (float*)(ws + DEG_OFF);
    float* Xp  = (float*)(ws + XP_OFF);
    unsigned int* hist = (unsigned int*)(ws + HIST_OFF);
    int* scal  = (int*)(ws + SCAL_OFF);
    float* S   = (float*)(ws + S_OFF);
    float* h   = (float*)(ws + H_OFF);
    float* hT  = (float*)(ws + HT_OFF);
    float* sq  = (float*)(ws + SQ_OFF);
    unsigned short* w2h = (unsigned short*)(ws + W2H_OFF);
    unsigned short* w2l = (unsigned short*)(ws + W2L_OFF);

    mil_init<<<818, 256, 0, stream>>>((unsigned int*)d_ws);
    mil_wprep<<<160, 256, 0, stream>>>(w2, w2h, w2l);
    mil_cnn<<<4096, 256, 0, stream>>>(x, w1, b1, w2h, w2l, b2, fcw, fcb, h, hT, sq);
    mil_colsum<<<50, 256, 0, stream>>>(hT, S);
    mil_hist<<<dim3(32, 32), 256, 0, stream>>>(hT, sq, hist);
    mil_scan<<<1, 64, 0, stream>>>(hist, scal);
    mil_agg<<<dim3(64, 8), 256, 0, stream>>>(h, hT, sq, scal, agg, deg);
    mil_sage<<<820, 256, 0, stream>>>(h, agg, deg, S, scal, relw, relb, rootw, Xp);
    mil_final<<<1, 64, 0, stream>>>(Xp, scal, relw, relb, rootw,
                                    l1w, l1b, l2w, l2b, (float*)d_out);
}

// Round 7
// 542.395 us; speedup vs baseline: 1.1522x; 1.1522x over previous
//
#include <hip/hip_runtime.h>
#include <hip/hip_bf16.h>

// ---------------- workspace layout (bytes) ----------------
#define AGG_OFF     0u          // f32[4096*50]  (zeroed)
#define DEG_OFF     819200u     // f32[4096]     (zeroed)
#define XP_OFF      835584u     // f32[64]       (zeroed)
#define HIST_OFF    835840u     // u32[257]      (zeroed)
#define SCAL_OFF    836992u     // i32[8]        (zeroed; written by scan)
#define S_OFF       837120u     // f32[50] colsum of h
#define H_OFF       1048576u    // f32[4096][50] row-major
#define HT_OFF      1867776u    // f32[50][4096] transposed
#define SQ_OFF      2686976u    // f32[4096] row squared-norms
#define BYTES_OFF   2703360u    // u8[4096][4096] bucket bytes (optional)
#define WS_NEED     (2703360ull + 16777216ull)

// ============================================================
// Kernel 0: zero the accumulator region of the workspace
// ============================================================
__global__ __launch_bounds__(256) void mil_init(unsigned int* __restrict__ w)
{
    w[(size_t)blockIdx.x * 256u + threadIdx.x] = 0u;
}

// ============================================================
// Kernel 1: per-instance LeNet -> h[4096][50], hT[50][4096], sq[4096]
// (round-4 proven f32 version; bias after maxpool = monotone-safe)
// ============================================================
__global__ __launch_bounds__(256) void mil_cnn(
    const float* __restrict__ x, const float* __restrict__ w1, const float* __restrict__ b1,
    const float* __restrict__ w2, const float* __restrict__ b2,
    const float* __restrict__ fcw, const float* __restrict__ fcb,
    float* __restrict__ hout, float* __restrict__ hT, float* __restrict__ sqout)
{
    __shared__ __align__(16) float img[784];
    __shared__ float w1s[500];
    __shared__ float b1s[20];
    __shared__ float b2s[50];
    __shared__ __align__(16) float pool1[20*144];
    __shared__ float w2s[50*4*25];
    __shared__ __align__(16) float pool2[800];
    __shared__ float hloc[50];

    const int n = blockIdx.x;
    const int t = threadIdx.x;

    const float* xin = x + (size_t)n * 784;
    for (int i = t; i < 784; i += 256) img[i] = xin[i];
    for (int i = t; i < 500; i += 256) w1s[i] = w1[i];
    if (t < 20) b1s[t] = b1[t];
    { int u = t - 32; if (u >= 0 && u < 50) b2s[u] = b2[u]; }
    __syncthreads();

    // ---- conv1 (5x5, 1->20) + relu + 2x2 maxpool -> pool1[20][12][12]
    if (t < 240) {
        const int c = t / 12, py = t % 12;
        float wr[25];
#pragma unroll
        for (int k = 0; k < 25; k++) wr[k] = w1s[c*25 + k];
        float acc0[24], acc1[24];
#pragma unroll
        for (int i = 0; i < 24; i++) { acc0[i] = 0.f; acc1[i] = 0.f; }
#pragma unroll
        for (int ky = 0; ky < 5; ky++) {
            const int yr = 2*py + ky;
            float ra[28], rb[28];
#pragma unroll
            for (int i = 0; i < 28; i++) ra[i] = img[yr*28 + i];
#pragma unroll
            for (int i = 0; i < 28; i++) rb[i] = img[yr*28 + 28 + i];
#pragma unroll
            for (int kx = 0; kx < 5; kx++) {
                const float wv = wr[ky*5 + kx];
#pragma unroll
                for (int xo = 0; xo < 24; xo++) {
                    acc0[xo] = fmaf(ra[xo+kx], wv, acc0[xo]);
                    acc1[xo] = fmaf(rb[xo+kx], wv, acc1[xo]);
                }
            }
        }
        const float bias = b1s[c];
#pragma unroll
        for (int px = 0; px < 12; px++) {
            float v = fmaxf(fmaxf(acc0[2*px], acc0[2*px+1]),
                            fmaxf(acc1[2*px], acc1[2*px+1]));
            pool1[c*144 + py*12 + px] = fmaxf(v + bias, 0.f);
        }
    }
    __syncthreads();

    // ---- conv2 (5x5, 20->50) + relu + pool -> pool2[50*16]; ci in 5 chunks of 4
    float acc2[16];
#pragma unroll
    for (int i = 0; i < 16; i++) acc2[i] = 0.f;
    const int c2 = t / 4, py2 = t % 4;   // valid when t < 200
    for (int cig = 0; cig < 5; cig++) {
        __syncthreads();
        for (int idx = t; idx < 5000; idx += 256) {
            const int cc = idx / 100, rem = idx % 100;
            w2s[idx] = w2[cc*500 + cig*100 + rem];
        }
        __syncthreads();
        if (t < 200) {
#pragma unroll
            for (int cl = 0; cl < 4; cl++) {
                const int cig4 = cig*4 + cl;
#pragma unroll
                for (int ky = 0; ky < 5; ky++) {
                    const int r = 2*py2 + ky;
                    float ra[12], rb[12];
#pragma unroll
                    for (int i = 0; i < 12; i++) ra[i] = pool1[cig4*144 + r*12 + i];
#pragma unroll
                    for (int i = 0; i < 12; i++) rb[i] = pool1[cig4*144 + (r+1)*12 + i];
#pragma unroll
                    for (int kx = 0; kx < 5; kx++) {
                        const float wv = w2s[(c2*4 + cl)*25 + ky*5 + kx];
#pragma unroll
                        for (int xo = 0; xo < 8; xo++) {
                            acc2[xo]   = fmaf(ra[xo+kx], wv, acc2[xo]);
                            acc2[8+xo] = fmaf(rb[xo+kx], wv, acc2[8+xo]);
                        }
                    }
                }
            }
        }
    }
    __syncthreads();
    if (t < 200) {
        const float bias = b2s[c2];
#pragma unroll
        for (int px = 0; px < 4; px++) {
            float v = fmaxf(fmaxf(acc2[2*px], acc2[2*px+1]),
                            fmaxf(acc2[8+2*px], acc2[8+2*px+1]));
            pool2[c2*16 + py2*4 + px] = fmaxf(v + bias, 0.f);
        }
    }
    __syncthreads();

    // ---- fc: one wave per o-slice
    {
        const int wv = t >> 6, lane = t & 63;
        for (int o = wv; o < 50; o += 4) {
            float acc = 0.f;
#pragma unroll
            for (int r = 0; r < 13; r++) {
                const int k = r*64 + lane;
                if (k < 800) acc = fmaf(fcw[o*800 + k], pool2[k], acc);
            }
#pragma unroll
            for (int off = 32; off > 0; off >>= 1) acc += __shfl_xor(acc, off);
            if (lane == 0) hloc[o] = fmaxf(acc + fcb[o], 0.f);
        }
    }
    __syncthreads();
    if (t < 50) {
        const float v = hloc[t];
        hout[(size_t)n*50 + t] = v;
        hT[(size_t)t*4096 + n] = v;
    }
    if (t < 64) {
        float s = (t < 50) ? hloc[t]*hloc[t] : 0.f;
#pragma unroll
        for (int off = 32; off > 0; off >>= 1) s += __shfl_xor(s, off);
        if (t == 0) sqout[n] = s;
    }
}

// ============================================================
// Kernel 1b: S[d] = sum_n h[n][d]
// ============================================================
__global__ __launch_bounds__(256) void mil_colsum(
    const float* __restrict__ hT, float* __restrict__ S)
{
    __shared__ float red[4];
    const int d = blockIdx.x, t = threadIdx.x;
    float s = 0.f;
    for (int nn = t; nn < 4096; nn += 256) s += hT[(size_t)d*4096 + nn];
#pragma unroll
    for (int off = 32; off > 0; off >>= 1) s += __shfl_xor(s, off);
    if ((t & 63) == 0) red[t >> 6] = s;
    __syncthreads();
    if (t == 0) S[d] = red[0] + red[1] + red[2] + red[3];
}

// ============================================================
// Kernel 2: pairwise distances -> histogram buckets + bucket bytes.
// 128x128 tile, 8x8/thread, per-pair LDS atomics (round-4 proven).
// byte = min(k,255), diag = 255; ambiguity only matters if kc==255
// (then scan flags fallback).
// ============================================================
__global__ __launch_bounds__(256, 3) void mil_hist(
    const float* __restrict__ hT, const float* __restrict__ sq,
    unsigned int* __restrict__ hist, unsigned char* __restrict__ bytesA,
    const int wb)
{
    __shared__ __align__(16) float hiT[6400];   // [50][128]
    __shared__ __align__(16) float hjT[6400];
    __shared__ float sqi[128], sqj[128];
    __shared__ unsigned int lh[257];

    const int t = threadIdx.x;
    const int i0 = blockIdx.x * 128, j0 = blockIdx.y * 128;

    for (int idx = t; idx < 6400; idx += 256) {
        const int c = idx >> 7, l = idx & 127;
        hiT[idx] = hT[(size_t)c*4096 + i0 + l];
        hjT[idx] = hT[(size_t)c*4096 + j0 + l];
    }
    if (t < 128) { sqi[t] = sq[i0 + t]; sqj[t] = sq[j0 + t]; }
    for (int idx = t; idx < 257; idx += 256) lh[idx] = 0;
    __syncthreads();

    const int ti = t >> 4, tj = t & 15;
    float acc[8][8];
#pragma unroll
    for (int a = 0; a < 8; a++)
#pragma unroll
        for (int b = 0; b < 8; b++) acc[a][b] = 0.f;

    for (int c = 0; c < 50; c++) {
        const float4 a0 = *(const float4*)&hiT[c*128 + ti*8];
        const float4 a1 = *(const float4*)&hiT[c*128 + ti*8 + 4];
        const float4 b0 = *(const float4*)&hjT[c*128 + tj*8];
        const float4 b1 = *(const float4*)&hjT[c*128 + tj*8 + 4];
        const float aa[8] = {a0.x,a0.y,a0.z,a0.w,a1.x,a1.y,a1.z,a1.w};
        const float bb[8] = {b0.x,b0.y,b0.z,b0.w,b1.x,b1.y,b1.z,b1.w};
#pragma unroll
        for (int a = 0; a < 8; a++)
#pragma unroll
            for (int b = 0; b < 8; b++)
                acc[a][b] = fmaf(aa[a], bb[b], acc[a][b]);
    }

    unsigned int cnt0 = 0;
#pragma unroll
    for (int a = 0; a < 8; a++) {
        unsigned pk0 = 0, pk1 = 0;
#pragma unroll
        for (int b = 0; b < 8; b++) {
            const int gi = i0 + ti*8 + a, gj = j0 + tj*8 + b;
            int kbyte = 255;
            if (gi != gj) {
                const float d2 = sqi[ti*8+a] + sqj[tj*8+b] - 2.f*acc[a][b];
                const float d = sqrtf(fmaxf(d2, 0.f));
                int k = (int)floorf((d - 3.5f)*2.f) + 1;
                k = k < 0 ? 0 : (k > 256 ? 256 : k);
                if (k > 0   && d <  3.5f + 0.5f*(float)(k-1)) k--;
                if (k < 256 && d >= 3.5f + 0.5f*(float)k)     k++;
                if (k == 0) cnt0++;
                else atomicAdd(&lh[k], 1u);
                kbyte = k < 255 ? k : 255;
            }
            if (b < 4) pk0 |= (unsigned)kbyte << (8*b);
            else       pk1 |= (unsigned)kbyte << (8*(b-4));
        }
        if (wb) {
            const int gi = i0 + ti*8 + a;
            *(uint2*)&bytesA[(size_t)gi*4096 + j0 + tj*8] = make_uint2(pk0, pk1);
        }
    }
#pragma unroll
    for (int off = 32; off > 0; off >>= 1) cnt0 += __shfl_xor(cnt0, off);
    if ((t & 63) == 0 && cnt0) atomicAdd(&lh[0], cnt0);
    __syncthreads();
    for (int idx = t; idx < 257; idx += 256)
        if (lh[idx]) atomicAdd(&hist[idx], lh[idx]);
}

// ============================================================
// Kernel 3: prefix-scan -> kc, nnz, complement flag, byte-fallback flag
// ============================================================
__global__ void mil_scan(const unsigned int* __restrict__ hist, int* __restrict__ scal)
{
    if (threadIdx.x == 0) {
        unsigned long long cum = 0, nz = 0;
        int kc = -1;
        for (int k = 0; k < 256; k++) {
            cum += hist[k];
            if (kc < 0 && cum >= 410ull) { kc = k; nz = cum; }  // ceil(0.1*4096)
        }
        if (kc < 0) { kc = 0; nz = hist[0]; }
        scal[0] = kc;
        scal[1] = (int)nz;
        scal[2] = (nz * 2ull > 16773120ull) ? 1 : 0;   // complement if >half dense
        scal[3] = (kc >= 255) ? 1 : 0;                 // byte path ambiguous
    }
}

// ============================================================
// Kernel 4a: byte-driven aggregate (no gram recompute).
// agg[i][d] += sum_{j in target set} h[j][d]; deg[i] = |set|.
// Target set = edges, or non-edges when complement mode.
// ============================================================
__global__ __launch_bounds__(256) void mil_agg_b(
    const float* __restrict__ h, const unsigned char* __restrict__ bytesA,
    const int* __restrict__ scal, float* __restrict__ agg, float* __restrict__ deg)
{
    __shared__ __align__(16) unsigned char bL[64*528];
    __shared__ __align__(16) float hsub[4096];      // [jj][d], d padded to 64
    if (scal[3] != 0) return;                        // fallback kernel handles
    const int t = threadIdx.x;
    const int i0 = blockIdx.x * 64;
    const int jg = blockIdx.y * 512;
    const int kc = scal[0];
    const bool inv = (scal[2] != 0);

    for (int idx = t; idx < 2048; idx += 256) {
        const int r = idx >> 5, c = idx & 31;
        *(uint4*)&bL[r*528 + c*16] =
            *(const uint4*)&bytesA[(size_t)(i0 + r)*4096 + jg + c*16];
    }

    const int il = t >> 2, dq = t & 3;
    const int gi = i0 + il;
    float accum[16];
#pragma unroll
    for (int i = 0; i < 16; i++) accum[i] = 0.f;
    int degc = 0;

    for (int js = 0; js < 8; js++) {
        __syncthreads();
        for (int idx = t; idx < 4096; idx += 256) {
            const int jj = idx >> 6, d = idx & 63;
            hsub[idx] = (d < 50) ? h[(size_t)(jg + js*64 + jj)*50 + d] : 0.f;
        }
        __syncthreads();
        const unsigned char* brow = &bL[il*528 + js*64];
        const int jbase = jg + js*64;
        for (int jj = 0; jj < 64; jj++) {
            const bool e = (jbase + jj != gi) && ((brow[jj] <= kc) != inv);
            if (!__any(e)) continue;          // fast path: whole-wave skip
            const float m = e ? 1.f : 0.f;
            if (e && dq == 0) degc++;
#pragma unroll
            for (int q = 0; q < 4; q++) {
                const float4 hv = *(const float4*)&hsub[jj*64 + dq*16 + q*4];
                accum[q*4+0] = fmaf(m, hv.x, accum[q*4+0]);
                accum[q*4+1] = fmaf(m, hv.y, accum[q*4+1]);
                accum[q*4+2] = fmaf(m, hv.z, accum[q*4+2]);
                accum[q*4+3] = fmaf(m, hv.w, accum[q*4+3]);
            }
        }
    }

#pragma unroll
    for (int q = 0; q < 4; q++)
#pragma unroll
        for (int rr = 0; rr < 4; rr++) {
            const int d = dq*16 + q*4 + rr;
            if (d < 50 && accum[q*4+rr] != 0.f)
                atomicAdd(&agg[(size_t)gi*50 + d], accum[q*4+rr]);
        }
    if (dq == 0 && degc) atomicAdd(&deg[gi], (float)degc);
}

// ============================================================
// Kernel 4b: recompute-gram aggregate (fallback; mode=1 -> only when
// byte path flagged unusable, mode=0 -> always)
// ============================================================
__global__ __launch_bounds__(256, 3) void mil_agg_r(
    const float* __restrict__ h, const float* __restrict__ hT, const float* __restrict__ sq,
    const int* __restrict__ scal, float* __restrict__ agg, float* __restrict__ deg,
    const int mode)
{
    __shared__ __align__(16) float hiT[3200];       // [50][64]
    __shared__ __align__(16) float hjT[3200];
    __shared__ float sqi[64], sqj[64];
    __shared__ __align__(16) float hsub[4096];
    __shared__ __align__(16) unsigned char mk[4096];

    if (mode == 1 && scal[3] == 0) return;   // byte kernel handled it
    const int t = threadIdx.x;
    const int i0 = blockIdx.x * 64;
    const float thr = 3.5f + 0.5f * (float)scal[0];
    const bool inv = (scal[2] != 0);

    for (int idx = t; idx < 3200; idx += 256) {
        const int c = idx >> 6, l = idx & 63;
        hiT[idx] = hT[(size_t)c*4096 + i0 + l];
    }
    if (t < 64) sqi[t] = sq[i0 + t];

    const int ti = t >> 4, tj = t & 15;
    const int il = t >> 2, dq = t & 3;
    float accum[16];
#pragma unroll
    for (int i = 0; i < 16; i++) accum[i] = 0.f;
    int degc = 0;

    for (int js = 0; js < 8; js++) {
        const int j0 = blockIdx.y * 512 + js * 64;
        __syncthreads();
        for (int idx = t; idx < 3200; idx += 256) {
            const int c = idx >> 6, l = idx & 63;
            hjT[idx] = hT[(size_t)c*4096 + j0 + l];
        }
        for (int idx = t; idx < 4096; idx += 256) {
            const int jj = idx >> 6, d = idx & 63;
            hsub[idx] = (d < 50) ? h[(size_t)(j0 + jj)*50 + d] : 0.f;
        }
        if (t < 64) sqj[t] = sq[j0 + t];
        __syncthreads();

        float acc[4][4];
#pragma unroll
        for (int a = 0; a < 4; a++)
#pragma unroll
            for (int b = 0; b < 4; b++) acc[a][b] = 0.f;
        for (int c = 0; c < 50; c++) {
            const float4 av = *(const float4*)&hiT[c*64 + ti*4];
            const float4 bv = *(const float4*)&hjT[c*64 + tj*4];
            const float aa[4] = {av.x, av.y, av.z, av.w};
            const float bb[4] = {bv.x, bv.y, bv.z, bv.w};
#pragma unroll
            for (int a = 0; a < 4; a++)
#pragma unroll
                for (int b = 0; b < 4; b++)
                    acc[a][b] = fmaf(aa[a], bb[b], acc[a][b]);
        }

#pragma unroll
        for (int b = 0; b < 4; b++) {
            unsigned char ob[4];
#pragma unroll
            for (int a = 0; a < 4; a++) {
                const int gi = i0 + ti*4 + a, gj = j0 + tj*4 + b;
                const float d2 = sqi[ti*4+a] + sqj[tj*4+b] - 2.f*acc[a][b];
                const float dd = sqrtf(fmaxf(d2, 0.f));
                const bool edge = (dd < thr);
                ob[a] = (gi != gj && (edge != inv)) ? 1 : 0;
            }
            *(uchar4*)&mk[(tj*4+b)*64 + ti*4] = make_uchar4(ob[0], ob[1], ob[2], ob[3]);
        }
        __syncthreads();

        for (int jj = 0; jj < 64; jj++) {
            const bool e = (mk[jj*64 + il] != 0);
            if (!__any(e)) continue;
            const float m = e ? 1.f : 0.f;
            if (e && dq == 0) degc++;
#pragma unroll
            for (int q = 0; q < 4; q++) {
                const float4 hv = *(const float4*)&hsub[jj*64 + dq*16 + q*4];
                accum[q*4+0] = fmaf(m, hv.x, accum[q*4+0]);
                accum[q*4+1] = fmaf(m, hv.y, accum[q*4+1]);
                accum[q*4+2] = fmaf(m, hv.z, accum[q*4+2]);
                accum[q*4+3] = fmaf(m, hv.w, accum[q*4+3]);
            }
        }
    }

    const int node = i0 + il;
#pragma unroll
    for (int q = 0; q < 4; q++)
#pragma unroll
        for (int rr = 0; rr < 4; rr++) {
            const int d = dq*16 + q*4 + rr;
            if (d < 50 && accum[q*4+rr] != 0.f)
                atomicAdd(&agg[(size_t)node*50 + d], accum[q*4+rr]);
        }
    if (dq == 0 && degc) atomicAdd(&deg[node], (float)degc);
}

// ============================================================
// Kernel 5: Z = leaky(mean-agg@relW^T + relb + h@rootW^T); Xp += colsum(Z)
// Complement correction: agg_true = S - h[i] - comp; deg_true = 4095 - compdeg
// ============================================================
__global__ __launch_bounds__(256) void mil_sage(
    const float* __restrict__ h, const float* __restrict__ agg, const float* __restrict__ deg,
    const float* __restrict__ S, const int* __restrict__ scal,
    const float* __restrict__ relw, const float* __restrict__ relb,
    const float* __restrict__ rootw, float* __restrict__ Xp)
{
    __shared__ float relT[2500];   // [c][d]
    __shared__ float rootT[2500];
    __shared__ float rb[50];
    __shared__ float hn[250], mn[250], zb[250];
    const int t = threadIdx.x;
    const int nb = blockIdx.x * 5;
    const bool inv = (scal[2] != 0);

    for (int idx = t; idx < 2500; idx += 256) {
        const int d = idx / 50, c = idx % 50;
        relT[c*50 + d]  = relw[idx];
        rootT[c*50 + d] = rootw[idx];
    }
    if (t < 50) rb[t] = relb[t];
    if (t < 250) {
        const int nl = t / 50, d = t % 50;
        const int node = nb + nl;
        if (node < 4096) {
            const float hv = h[(size_t)node*50 + d];
            float av = agg[(size_t)node*50 + d];
            float dg = deg[node];
            if (inv) { av = S[d] - hv - av; dg = 4095.f - dg; }
            hn[t] = hv;
            mn[t] = av / fmaxf(dg, 1.f);
        } else { hn[t] = 0.f; mn[t] = 0.f; }
    }
    __syncthreads();
    if (t < 250) {
        const int nl = t / 50, d = t % 50;
        float z = rb[d];
        for (int c = 0; c < 50; c++) {
            z = fmaf(mn[nl*50 + c], relT[c*50 + d], z);
            z = fmaf(hn[nl*50 + c], rootT[c*50 + d], z);
        }
        z = z > 0.f ? z : 0.01f * z;
        zb[t] = (nb + nl < 4096) ? z : 0.f;
    }
    __syncthreads();
    if (t < 50) {
        float s = 0.f;
#pragma unroll
        for (int nl = 0; nl < 5; nl++) s += zb[nl*50 + t];
        atomicAdd(&Xp[t], s);
    }
}

// ============================================================
// Kernel 6: pooled sage + lin1 + lin2 + softmax -> out[3] (f32)
// ============================================================
__global__ void mil_final(
    const float* __restrict__ Xp, const int* __restrict__ scal,
    const float* __restrict__ relw, const float* __restrict__ relb,
    const float* __restrict__ rootw,
    const float* __restrict__ l1w, const float* __restrict__ l1b,
    const float* __restrict__ l2w, const float* __restrict__ l2b,
    float* __restrict__ out)
{
    __shared__ float xp[50], x2[50], v1[25], v2[2];
    const int t = threadIdx.x;
    if (t < 50) xp[t] = Xp[t];
    __syncthreads();
    const float adjp = (float)scal[1];
    const float dmax = fmaxf(adjp, 1.f);
    if (t < 50) {
        float z = relb[t];
        for (int c = 0; c < 50; c++) {
            const float mnc = (adjp * xp[c]) / dmax;
            z = fmaf(mnc,   relw[t*50 + c], z);
            z = fmaf(xp[c], rootw[t*50 + c], z);
        }
        x2[t] = z > 0.f ? z : 0.01f*z;
    }
    __syncthreads();
    if (t < 25) {
        float v = l1b[t];
        for (int c = 0; c < 50; c++) v = fmaf(l1w[t*50 + c], x2[c], v);
        v1[t] = v > 0.f ? v : 0.01f*v;
    }
    __syncthreads();
    if (t < 2) {
        float v = l2b[t];
        for (int c = 0; c < 25; c++) v = fmaf(l2w[t*25 + c], v1[c], v);
        v2[t] = v > 0.f ? v : 0.01f*v;
    }
    __syncthreads();
    if (t == 0) {
        const float a = v2[0], b = v2[1];
        const float mx = fmaxf(a, b);
        const float e0 = expf(a - mx), e1 = expf(b - mx);
        const float s = e0 + e1;
        const float p0 = e0 / s, p1 = e1 / s;
        const float pm = fmaxf(p0, p1);
        const float am = (p1 > p0) ? 1.f : 0.f;
        const int nnz = scal[1];
        const float l1v = sqrtf((float)(16777216 - nnz)) / 16777216.f;
        out[0] = pm;
        out[1] = am;
        out[2] = l1v;
    }
}

// ============================================================
extern "C" void kernel_launch(void* const* d_in, const int* in_sizes, int n_in,
                              void* d_out, int out_size, void* d_ws, size_t ws_size,
                              hipStream_t stream)
{
    (void)in_sizes; (void)n_in; (void)out_size;
    const float* x     = (const float*)d_in[0];
    const float* w1    = (const float*)d_in[1];
    const float* b1    = (const float*)d_in[2];
    const float* w2    = (const float*)d_in[3];
    const float* b2    = (const float*)d_in[4];
    const float* fcw   = (const float*)d_in[5];
    const float* fcb   = (const float*)d_in[6];
    const float* relw  = (const float*)d_in[7];
    const float* relb  = (const float*)d_in[8];
    const float* rootw = (const float*)d_in[9];
    // d_in[10..14] (pool_*, mlp_*) are dead: softmax over a length-1 axis == 1
    const float* l1w   = (const float*)d_in[15];
    const float* l1b   = (const float*)d_in[16];
    const float* l2w   = (const float*)d_in[17];
    const float* l2b   = (const float*)d_in[18];

    char* ws = (char*)d_ws;
    float* agg = (float*)(ws + AGG_OFF);
    float* deg = (float*)(ws + DEG_OFF);
    float* Xp  = (float*)(ws + XP_OFF);
    unsigned int* hist = (unsigned int*)(ws + HIST_OFF);
    int* scal  = (int*)(ws + SCAL_OFF);
    float* S   = (float*)(ws + S_OFF);
    float* h   = (float*)(ws + H_OFF);
    float* hT  = (float*)(ws + HT_OFF);
    float* sq  = (float*)(ws + SQ_OFF);
    unsigned char* bytesA = (unsigned char*)(ws + BYTES_OFF);

    const int have_bytes = (ws_size >= WS_NEED) ? 1 : 0;  // constant per process

    mil_init<<<818, 256, 0, stream>>>((unsigned int*)d_ws);
    mil_cnn<<<4096, 256, 0, stream>>>(x, w1, b1, w2, b2, fcw, fcb, h, hT, sq);
    mil_colsum<<<50, 256, 0, stream>>>(hT, S);
    mil_hist<<<dim3(32, 32), 256, 0, stream>>>(hT, sq, hist, bytesA, have_bytes);
    mil_scan<<<1, 64, 0, stream>>>(hist, scal);
    if (have_bytes) {
        mil_agg_b<<<dim3(64, 8), 256, 0, stream>>>(h, bytesA, scal, agg, deg);
        mil_agg_r<<<dim3(64, 8), 256, 0, stream>>>(h, hT, sq, scal, agg, deg, 1);
    } else {
        mil_agg_r<<<dim3(64, 8), 256, 0, stream>>>(h, hT, sq, scal, agg, deg, 0);
    }
    mil_sage<<<820, 256, 0, stream>>>(h, agg, deg, S, scal, relw, relb, rootw, Xp);
    mil_final<<<1, 64, 0, stream>>>(Xp, scal, relw, relb, rootw,
                                    l1w, l1b, l2w, l2b, (float*)d_out);
}

// Round 8
// 540.463 us; speedup vs baseline: 1.1563x; 1.0036x over previous
//
#include <hip/hip_runtime.h>
#include <hip/hip_bf16.h>

// ---------------- workspace layout (bytes) ----------------
#define AGG_OFF     0u          // f32[4096*50]  (zeroed)
#define DEG_OFF     819200u     // f32[4096]     (zeroed)
#define XP_OFF      835584u     // f32[64]       (zeroed)
#define HIST_OFF    835840u     // u32[257]      (zeroed)
#define SCAL_OFF    836992u     // i32[8]        (zeroed; written by scan)
#define S_OFF       837120u     // f32[50] colsum of h
#define H_OFF       1048576u    // f32[4096][50] row-major
#define HT_OFF      1867776u    // f32[50][4096] transposed
#define SQ_OFF      2686976u    // f32[4096] row squared-norms
#define BYTES_OFF   2703360u    // u8[4096][4096] bucket bytes (optional)
#define WS_NEED     (2703360ull + 16777216ull)

// ============================================================
// Kernel 0: zero the accumulator region of the workspace
// ============================================================
__global__ __launch_bounds__(256) void mil_init(unsigned int* __restrict__ w)
{
    w[(size_t)blockIdx.x * 256u + threadIdx.x] = 0u;
}

// ============================================================
// Kernel 1: per-instance LeNet -> h[4096][50], hT[50][4096], sq[4096]
// Row-rolled convs (each input row read once, applied to taps j and j-1),
// float4 LDS loads, img/w2s LDS overlap, 2-ci weight chunks (28-padded).
// Per-accumulator FMA order identical to round-4 -> bitwise-same h.
// ============================================================
__global__ __launch_bounds__(256, 5) void mil_cnn(
    const float* __restrict__ x, const float* __restrict__ w1, const float* __restrict__ b1,
    const float* __restrict__ w2, const float* __restrict__ b2,
    const float* __restrict__ fcw, const float* __restrict__ fcb,
    float* __restrict__ hout, float* __restrict__ hT, float* __restrict__ sqout)
{
    __shared__ __align__(16) float pool1[20*144];
    __shared__ __align__(16) float pool2[800];
    __shared__ float b1s[20];
    __shared__ float b2s[64];
    __shared__ float hloc[64];
    __shared__ __align__(16) float ovl[2800]; // conv1: img[784]+w1s[500]; conv2: w2s[50][2][28]

    float* img = ovl;
    float* w1s = ovl + 784;
    float* w2s = ovl;

    const int n = blockIdx.x;
    const int t = threadIdx.x;

    const float* xin = x + (size_t)n * 784;
    for (int i = t; i < 784; i += 256) img[i] = xin[i];
    for (int i = t; i < 500; i += 256) w1s[i] = w1[i];
    if (t < 20) b1s[t] = b1[t];
    { int u = t - 32; if (u >= 0 && u < 50) b2s[u] = b2[u]; }
    __syncthreads();

    // ---- conv1 (5x5, 1->20) + relu + 2x2 maxpool -> pool1[20][12][12]
    if (t < 240) {
        const int c = t / 12, py = t % 12;
        float wr[25];
#pragma unroll
        for (int k = 0; k < 25; k++) wr[k] = w1s[c*25 + k];
        float acc0[24], acc1[24];
#pragma unroll
        for (int i = 0; i < 24; i++) { acc0[i] = 0.f; acc1[i] = 0.f; }
#pragma unroll
        for (int j = 0; j < 6; j++) {            // input rows 2py..2py+5, once each
            float rr[28];
            const float* rp = &img[(2*py + j)*28];   // 16B-aligned: 28%4==0
#pragma unroll
            for (int q = 0; q < 7; q++) {
                const float4 v = *(const float4*)(rp + 4*q);
                rr[4*q+0] = v.x; rr[4*q+1] = v.y; rr[4*q+2] = v.z; rr[4*q+3] = v.w;
            }
            if (j <= 4) {                         // out row 2py, tap ky=j
#pragma unroll
                for (int kx = 0; kx < 5; kx++) {
                    const float wv = wr[j*5 + kx];
#pragma unroll
                    for (int xo = 0; xo < 24; xo++)
                        acc0[xo] = fmaf(rr[xo+kx], wv, acc0[xo]);
                }
            }
            if (j >= 1) {                         // out row 2py+1, tap ky=j-1
#pragma unroll
                for (int kx = 0; kx < 5; kx++) {
                    const float wv = wr[(j-1)*5 + kx];
#pragma unroll
                    for (int xo = 0; xo < 24; xo++)
                        acc1[xo] = fmaf(rr[xo+kx], wv, acc1[xo]);
                }
            }
        }
        const float bias = b1s[c];
#pragma unroll
        for (int px = 0; px < 12; px++) {
            float v = fmaxf(fmaxf(acc0[2*px], acc0[2*px+1]),
                            fmaxf(acc1[2*px], acc1[2*px+1]));
            pool1[c*144 + py*12 + px] = fmaxf(v + bias, 0.f);
        }
    }
    __syncthreads();

    // ---- conv2 (5x5, 20->50) + relu + pool; 10 chunks of 2 input channels
    float acc2[16];
#pragma unroll
    for (int i = 0; i < 16; i++) acc2[i] = 0.f;
    const int c2 = t / 4, py2 = t % 4;   // valid when t < 200
    for (int cig = 0; cig < 10; cig++) {
        __syncthreads();
        for (int idx = t; idx < 2800; idx += 256) {
            const int cc = idx / 56, r = idx % 56;
            const int cl = r / 28, k = r % 28;
            w2s[idx] = (k < 25) ? w2[cc*500 + (cig*2 + cl)*25 + k] : 0.f;
        }
        __syncthreads();
        if (t < 200) {
#pragma unroll
            for (int cl = 0; cl < 2; cl++) {
                const int ci = cig*2 + cl;
                float wreg[25];
                const float* wp = &w2s[c2*56 + cl*28];  // 16B-aligned
#pragma unroll
                for (int q = 0; q < 6; q++) {
                    const float4 v = *(const float4*)(wp + 4*q);
                    wreg[4*q+0] = v.x; wreg[4*q+1] = v.y;
                    wreg[4*q+2] = v.z; wreg[4*q+3] = v.w;
                }
                wreg[24] = wp[24];
#pragma unroll
                for (int j = 0; j < 6; j++) {    // input rows 2py2..2py2+5, once
                    float rr[12];
                    const float* rp = &pool1[ci*144 + (2*py2 + j)*12]; // 16B-aligned
#pragma unroll
                    for (int q = 0; q < 3; q++) {
                        const float4 v = *(const float4*)(rp + 4*q);
                        rr[4*q+0] = v.x; rr[4*q+1] = v.y;
                        rr[4*q+2] = v.z; rr[4*q+3] = v.w;
                    }
                    if (j <= 4) {                 // out row 2py2, tap ky=j
#pragma unroll
                        for (int kx = 0; kx < 5; kx++) {
                            const float wv = wreg[j*5 + kx];
#pragma unroll
                            for (int xo = 0; xo < 8; xo++)
                                acc2[xo] = fmaf(rr[xo+kx], wv, acc2[xo]);
                        }
                    }
                    if (j >= 1) {                 // out row 2py2+1, tap ky=j-1
#pragma unroll
                        for (int kx = 0; kx < 5; kx++) {
                            const float wv = wreg[(j-1)*5 + kx];
#pragma unroll
                            for (int xo = 0; xo < 8; xo++)
                                acc2[8+xo] = fmaf(rr[xo+kx], wv, acc2[8+xo]);
                        }
                    }
                }
            }
        }
    }
    __syncthreads();
    if (t < 200) {
        const float bias = b2s[c2];
#pragma unroll
        for (int px = 0; px < 4; px++) {
            float v = fmaxf(fmaxf(acc2[2*px], acc2[2*px+1]),
                            fmaxf(acc2[8+2*px], acc2[8+2*px+1]));
            pool2[c2*16 + py2*4 + px] = fmaxf(v + bias, 0.f);
        }
    }
    __syncthreads();

    // ---- fc: one wave per o-slice
    {
        const int wv = t >> 6, lane = t & 63;
        for (int o = wv; o < 50; o += 4) {
            float acc = 0.f;
#pragma unroll
            for (int r = 0; r < 13; r++) {
                const int k = r*64 + lane;
                if (k < 800) acc = fmaf(fcw[o*800 + k], pool2[k], acc);
            }
#pragma unroll
            for (int off = 32; off > 0; off >>= 1) acc += __shfl_xor(acc, off);
            if (lane == 0) hloc[o] = fmaxf(acc + fcb[o], 0.f);
        }
    }
    __syncthreads();
    if (t < 50) {
        const float v = hloc[t];
        hout[(size_t)n*50 + t] = v;
        hT[(size_t)t*4096 + n] = v;
    }
    if (t < 64) {
        float s = (t < 50) ? hloc[t]*hloc[t] : 0.f;
#pragma unroll
        for (int off = 32; off > 0; off >>= 1) s += __shfl_xor(s, off);
        if (t == 0) sqout[n] = s;
    }
}

// ============================================================
// Kernel 1b: S[d] = sum_n h[n][d]
// ============================================================
__global__ __launch_bounds__(256) void mil_colsum(
    const float* __restrict__ hT, float* __restrict__ S)
{
    __shared__ float red[4];
    const int d = blockIdx.x, t = threadIdx.x;
    float s = 0.f;
    for (int nn = t; nn < 4096; nn += 256) s += hT[(size_t)d*4096 + nn];
#pragma unroll
    for (int off = 32; off > 0; off >>= 1) s += __shfl_xor(s, off);
    if ((t & 63) == 0) red[t >> 6] = s;
    __syncthreads();
    if (t == 0) S[d] = red[0] + red[1] + red[2] + red[3];
}

// ============================================================
// Kernel 2: pairwise distances -> histogram buckets + bucket bytes.
// ============================================================
__global__ __launch_bounds__(256, 3) void mil_hist(
    const float* __restrict__ hT, const float* __restrict__ sq,
    unsigned int* __restrict__ hist, unsigned char* __restrict__ bytesA,
    const int wb)
{
    __shared__ __align__(16) float hiT[6400];   // [50][128]
    __shared__ __align__(16) float hjT[6400];
    __shared__ float sqi[128], sqj[128];
    __shared__ unsigned int lh[257];

    const int t = threadIdx.x;
    const int i0 = blockIdx.x * 128, j0 = blockIdx.y * 128;

    for (int idx = t; idx < 6400; idx += 256) {
        const int c = idx >> 7, l = idx & 127;
        hiT[idx] = hT[(size_t)c*4096 + i0 + l];
        hjT[idx] = hT[(size_t)c*4096 + j0 + l];
    }
    if (t < 128) { sqi[t] = sq[i0 + t]; sqj[t] = sq[j0 + t]; }
    for (int idx = t; idx < 257; idx += 256) lh[idx] = 0;
    __syncthreads();

    const int ti = t >> 4, tj = t & 15;
    float acc[8][8];
#pragma unroll
    for (int a = 0; a < 8; a++)
#pragma unroll
        for (int b = 0; b < 8; b++) acc[a][b] = 0.f;

    for (int c = 0; c < 50; c++) {
        const float4 a0 = *(const float4*)&hiT[c*128 + ti*8];
        const float4 a1 = *(const float4*)&hiT[c*128 + ti*8 + 4];
        const float4 b0 = *(const float4*)&hjT[c*128 + tj*8];
        const float4 b1 = *(const float4*)&hjT[c*128 + tj*8 + 4];
        const float aa[8] = {a0.x,a0.y,a0.z,a0.w,a1.x,a1.y,a1.z,a1.w};
        const float bb[8] = {b0.x,b0.y,b0.z,b0.w,b1.x,b1.y,b1.z,b1.w};
#pragma unroll
        for (int a = 0; a < 8; a++)
#pragma unroll
            for (int b = 0; b < 8; b++)
                acc[a][b] = fmaf(aa[a], bb[b], acc[a][b]);
    }

    unsigned int cnt0 = 0;
#pragma unroll
    for (int a = 0; a < 8; a++) {
        unsigned pk0 = 0, pk1 = 0;
#pragma unroll
        for (int b = 0; b < 8; b++) {
            const int gi = i0 + ti*8 + a, gj = j0 + tj*8 + b;
            int kbyte = 255;
            if (gi != gj) {
                const float d2 = sqi[ti*8+a] + sqj[tj*8+b] - 2.f*acc[a][b];
                const float d = sqrtf(fmaxf(d2, 0.f));
                int k = (int)floorf((d - 3.5f)*2.f) + 1;
                k = k < 0 ? 0 : (k > 256 ? 256 : k);
                if (k > 0   && d <  3.5f + 0.5f*(float)(k-1)) k--;
                if (k < 256 && d >= 3.5f + 0.5f*(float)k)     k++;
                if (k == 0) cnt0++;
                else atomicAdd(&lh[k], 1u);
                kbyte = k < 255 ? k : 255;
            }
            if (b < 4) pk0 |= (unsigned)kbyte << (8*b);
            else       pk1 |= (unsigned)kbyte << (8*(b-4));
        }
        if (wb) {
            const int gi = i0 + ti*8 + a;
            *(uint2*)&bytesA[(size_t)gi*4096 + j0 + tj*8] = make_uint2(pk0, pk1);
        }
    }
#pragma unroll
    for (int off = 32; off > 0; off >>= 1) cnt0 += __shfl_xor(cnt0, off);
    if ((t & 63) == 0 && cnt0) atomicAdd(&lh[0], cnt0);
    __syncthreads();
    for (int idx = t; idx < 257; idx += 256)
        if (lh[idx]) atomicAdd(&hist[idx], lh[idx]);
}

// ============================================================
// Kernel 3: prefix-scan -> kc, nnz, complement flag, byte-fallback flag
// ============================================================
__global__ void mil_scan(const unsigned int* __restrict__ hist, int* __restrict__ scal)
{
    if (threadIdx.x == 0) {
        unsigned long long cum = 0, nz = 0;
        int kc = -1;
        for (int k = 0; k < 256; k++) {
            cum += hist[k];
            if (kc < 0 && cum >= 410ull) { kc = k; nz = cum; }  // ceil(0.1*4096)
        }
        if (kc < 0) { kc = 0; nz = hist[0]; }
        scal[0] = kc;
        scal[1] = (int)nz;
        scal[2] = (nz * 2ull > 16773120ull) ? 1 : 0;   // complement if >half dense
        scal[3] = (kc >= 255) ? 1 : 0;                 // byte path ambiguous
    }
}

// ============================================================
// Kernel 4a: byte-driven aggregate (no gram recompute).
// ============================================================
__global__ __launch_bounds__(256) void mil_agg_b(
    const float* __restrict__ h, const unsigned char* __restrict__ bytesA,
    const int* __restrict__ scal, float* __restrict__ agg, float* __restrict__ deg)
{
    __shared__ __align__(16) unsigned char bL[64*528];
    __shared__ __align__(16) float hsub[4096];      // [jj][d], d padded to 64
    if (scal[3] != 0) return;                        // fallback kernel handles
    const int t = threadIdx.x;
    const int i0 = blockIdx.x * 64;
    const int jg = blockIdx.y * 512;
    const int kc = scal[0];
    const bool inv = (scal[2] != 0);

    for (int idx = t; idx < 2048; idx += 256) {
        const int r = idx >> 5, c = idx & 31;
        *(uint4*)&bL[r*528 + c*16] =
            *(const uint4*)&bytesA[(size_t)(i0 + r)*4096 + jg + c*16];
    }

    const int il = t >> 2, dq = t & 3;
    const int gi = i0 + il;
    float accum[16];
#pragma unroll
    for (int i = 0; i < 16; i++) accum[i] = 0.f;
    int degc = 0;

    for (int js = 0; js < 8; js++) {
        __syncthreads();
        for (int idx = t; idx < 4096; idx += 256) {
            const int jj = idx >> 6, d = idx & 63;
            hsub[idx] = (d < 50) ? h[(size_t)(jg + js*64 + jj)*50 + d] : 0.f;
        }
        __syncthreads();
        const unsigned char* brow = &bL[il*528 + js*64];
        const int jbase = jg + js*64;
        for (int jj = 0; jj < 64; jj++) {
            const bool e = (jbase + jj != gi) && ((brow[jj] <= kc) != inv);
            if (!__any(e)) continue;          // fast path: whole-wave skip
            const float m = e ? 1.f : 0.f;
            if (e && dq == 0) degc++;
#pragma unroll
            for (int q = 0; q < 4; q++) {
                const float4 hv = *(const float4*)&hsub[jj*64 + dq*16 + q*4];
                accum[q*4+0] = fmaf(m, hv.x, accum[q*4+0]);
                accum[q*4+1] = fmaf(m, hv.y, accum[q*4+1]);
                accum[q*4+2] = fmaf(m, hv.z, accum[q*4+2]);
                accum[q*4+3] = fmaf(m, hv.w, accum[q*4+3]);
            }
        }
    }

#pragma unroll
    for (int q = 0; q < 4; q++)
#pragma unroll
        for (int rr = 0; rr < 4; rr++) {
            const int d = dq*16 + q*4 + rr;
            if (d < 50 && accum[q*4+rr] != 0.f)
                atomicAdd(&agg[(size_t)gi*50 + d], accum[q*4+rr]);
        }
    if (dq == 0 && degc) atomicAdd(&deg[gi], (float)degc);
}

// ============================================================
// Kernel 4b: recompute-gram aggregate (fallback)
// ============================================================
__global__ __launch_bounds__(256, 3) void mil_agg_r(
    const float* __restrict__ h, const float* __restrict__ hT, const float* __restrict__ sq,
    const int* __restrict__ scal, float* __restrict__ agg, float* __restrict__ deg,
    const int mode)
{
    __shared__ __align__(16) float hiT[3200];       // [50][64]
    __shared__ __align__(16) float hjT[3200];
    __shared__ float sqi[64], sqj[64];
    __shared__ __align__(16) float hsub[4096];
    __shared__ __align__(16) unsigned char mk[4096];

    if (mode == 1 && scal[3] == 0) return;   // byte kernel handled it
    const int t = threadIdx.x;
    const int i0 = blockIdx.x * 64;
    const float thr = 3.5f + 0.5f * (float)scal[0];
    const bool inv = (scal[2] != 0);

    for (int idx = t; idx < 3200; idx += 256) {
        const int c = idx >> 6, l = idx & 63;
        hiT[idx] = hT[(size_t)c*4096 + i0 + l];
    }
    if (t < 64) sqi[t] = sq[i0 + t];

    const int ti = t >> 4, tj = t & 15;
    const int il = t >> 2, dq = t & 3;
    float accum[16];
#pragma unroll
    for (int i = 0; i < 16; i++) accum[i] = 0.f;
    int degc = 0;

    for (int js = 0; js < 8; js++) {
        const int j0 = blockIdx.y * 512 + js * 64;
        __syncthreads();
        for (int idx = t; idx < 3200; idx += 256) {
            const int c = idx >> 6, l = idx & 63;
            hjT[idx] = hT[(size_t)c*4096 + j0 + l];
        }
        for (int idx = t; idx < 4096; idx += 256) {
            const int jj = idx >> 6, d = idx & 63;
            hsub[idx] = (d < 50) ? h[(size_t)(j0 + jj)*50 + d] : 0.f;
        }
        if (t < 64) sqj[t] = sq[j0 + t];
        __syncthreads();

        float acc[4][4];
#pragma unroll
        for (int a = 0; a < 4; a++)
#pragma unroll
            for (int b = 0; b < 4; b++) acc[a][b] = 0.f;
        for (int c = 0; c < 50; c++) {
            const float4 av = *(const float4*)&hiT[c*64 + ti*4];
            const float4 bv = *(const float4*)&hjT[c*64 + tj*4];
            const float aa[4] = {av.x, av.y, av.z, av.w};
            const float bb[4] = {bv.x, bv.y, bv.z, bv.w};
#pragma unroll
            for (int a = 0; a < 4; a++)
#pragma unroll
                for (int b = 0; b < 4; b++)
                    acc[a][b] = fmaf(aa[a], bb[b], acc[a][b]);
        }

#pragma unroll
        for (int b = 0; b < 4; b++) {
            unsigned char ob[4];
#pragma unroll
            for (int a = 0; a < 4; a++) {
                const int gi = i0 + ti*4 + a, gj = j0 + tj*4 + b;
                const float d2 = sqi[ti*4+a] + sqj[tj*4+b] - 2.f*acc[a][b];
                const float dd = sqrtf(fmaxf(d2, 0.f));
                const bool edge = (dd < thr);
                ob[a] = (gi != gj && (edge != inv)) ? 1 : 0;
            }
            *(uchar4*)&mk[(tj*4+b)*64 + ti*4] = make_uchar4(ob[0], ob[1], ob[2], ob[3]);
        }
        __syncthreads();

        for (int jj = 0; jj < 64; jj++) {
            const bool e = (mk[jj*64 + il] != 0);
            if (!__any(e)) continue;
            const float m = e ? 1.f : 0.f;
            if (e && dq == 0) degc++;
#pragma unroll
            for (int q = 0; q < 4; q++) {
                const float4 hv = *(const float4*)&hsub[jj*64 + dq*16 + q*4];
                accum[q*4+0] = fmaf(m, hv.x, accum[q*4+0]);
                accum[q*4+1] = fmaf(m, hv.y, accum[q*4+1]);
                accum[q*4+2] = fmaf(m, hv.z, accum[q*4+2]);
                accum[q*4+3] = fmaf(m, hv.w, accum[q*4+3]);
            }
        }
    }

    const int node = i0 + il;
#pragma unroll
    for (int q = 0; q < 4; q++)
#pragma unroll
        for (int rr = 0; rr < 4; rr++) {
            const int d = dq*16 + q*4 + rr;
            if (d < 50 && accum[q*4+rr] != 0.f)
                atomicAdd(&agg[(size_t)node*50 + d], accum[q*4+rr]);
        }
    if (dq == 0 && degc) atomicAdd(&deg[node], (float)degc);
}

// ============================================================
// Kernel 5: Z = leaky(mean-agg@relW^T + relb + h@rootW^T); Xp += colsum(Z)
// ============================================================
__global__ __launch_bounds__(256) void mil_sage(
    const float* __restrict__ h, const float* __restrict__ agg, const float* __restrict__ deg,
    const float* __restrict__ S, const int* __restrict__ scal,
    const float* __restrict__ relw, const float* __restrict__ relb,
    const float* __restrict__ rootw, float* __restrict__ Xp)
{
    __shared__ float relT[2500];   // [c][d]
    __shared__ float rootT[2500];
    __shared__ float rb[50];
    __shared__ float hn[250], mn[250], zb[250];
    const int t = threadIdx.x;
    const int nb = blockIdx.x * 5;
    const bool inv = (scal[2] != 0);

    for (int idx = t; idx < 2500; idx += 256) {
        const int d = idx / 50, c = idx % 50;
        relT[c*50 + d]  = relw[idx];
        rootT[c*50 + d] = rootw[idx];
    }
    if (t < 50) rb[t] = relb[t];
    if (t < 250) {
        const int nl = t / 50, d = t % 50;
        const int node = nb + nl;
        if (node < 4096) {
            const float hv = h[(size_t)node*50 + d];
            float av = agg[(size_t)node*50 + d];
            float dg = deg[node];
            if (inv) { av = S[d] - hv - av; dg = 4095.f - dg; }
            hn[t] = hv;
            mn[t] = av / fmaxf(dg, 1.f);
        } else { hn[t] = 0.f; mn[t] = 0.f; }
    }
    __syncthreads();
    if (t < 250) {
        const int nl = t / 50, d = t % 50;
        float z = rb[d];
        for (int c = 0; c < 50; c++) {
            z = fmaf(mn[nl*50 + c], relT[c*50 + d], z);
            z = fmaf(hn[nl*50 + c], rootT[c*50 + d], z);
        }
        z = z > 0.f ? z : 0.01f * z;
        zb[t] = (nb + nl < 4096) ? z : 0.f;
    }
    __syncthreads();
    if (t < 50) {
        float s = 0.f;
#pragma unroll
        for (int nl = 0; nl < 5; nl++) s += zb[nl*50 + t];
        atomicAdd(&Xp[t], s);
    }
}

// ============================================================
// Kernel 6: pooled sage + lin1 + lin2 + softmax -> out[3] (f32)
// ============================================================
__global__ void mil_final(
    const float* __restrict__ Xp, const int* __restrict__ scal,
    const float* __restrict__ relw, const float* __restrict__ relb,
    const float* __restrict__ rootw,
    const float* __restrict__ l1w, const float* __restrict__ l1b,
    const float* __restrict__ l2w, const float* __restrict__ l2b,
    float* __restrict__ out)
{
    __shared__ float xp[50], x2[50], v1[25], v2[2];
    const int t = threadIdx.x;
    if (t < 50) xp[t] = Xp[t];
    __syncthreads();
    const float adjp = (float)scal[1];
    const float dmax = fmaxf(adjp, 1.f);
    if (t < 50) {
        float z = relb[t];
        for (int c = 0; c < 50; c++) {
            const float mnc = (adjp * xp[c]) / dmax;
            z = fmaf(mnc,   relw[t*50 + c], z);
            z = fmaf(xp[c], rootw[t*50 + c], z);
        }
        x2[t] = z > 0.f ? z : 0.01f*z;
    }
    __syncthreads();
    if (t < 25) {
        float v = l1b[t];
        for (int c = 0; c < 50; c++) v = fmaf(l1w[t*50 + c], x2[c], v);
        v1[t] = v > 0.f ? v : 0.01f*v;
    }
    __syncthreads();
    if (t < 2) {
        float v = l2b[t];
        for (int c = 0; c < 25; c++) v = fmaf(l2w[t*25 + c], v1[c], v);
        v2[t] = v > 0.f ? v : 0.01f*v;
    }
    __syncthreads();
    if (t == 0) {
        const float a = v2[0], b = v2[1];
        const float mx = fmaxf(a, b);
        const float e0 = expf(a - mx), e1 = expf(b - mx);
        const float s = e0 + e1;
        const float p0 = e0 / s, p1 = e1 / s;
        const float pm = fmaxf(p0, p1);
        const float am = (p1 > p0) ? 1.f : 0.f;
        const int nnz = scal[1];
        const float l1v = sqrtf((float)(16777216 - nnz)) / 16777216.f;
        out[0] = pm;
        out[1] = am;
        out[2] = l1v;
    }
}

// ============================================================
extern "C" void kernel_launch(void* const* d_in, const int* in_sizes, int n_in,
                              void* d_out, int out_size, void* d_ws, size_t ws_size,
                              hipStream_t stream)
{
    (void)in_sizes; (void)n_in; (void)out_size;
    const float* x     = (const float*)d_in[0];
    const float* w1    = (const float*)d_in[1];
    const float* b1    = (const float*)d_in[2];
    const float* w2    = (const float*)d_in[3];
    const float* b2    = (const float*)d_in[4];
    const float* fcw   = (const float*)d_in[5];
    const float* fcb   = (const float*)d_in[6];
    const float* relw  = (const float*)d_in[7];
    const float* relb  = (const float*)d_in[8];
    const float* rootw = (const float*)d_in[9];
    // d_in[10..14] (pool_*, mlp_*) are dead: softmax over a length-1 axis == 1
    const float* l1w   = (const float*)d_in[15];
    const float* l1b   = (const float*)d_in[16];
    const float* l2w   = (const float*)d_in[17];
    const float* l2b   = (const float*)d_in[18];

    char* ws = (char*)d_ws;
    float* agg = (float*)(ws + AGG_OFF);
    float* deg = (float*)(ws + DEG_OFF);
    float* Xp  = (float*)(ws + XP_OFF);
    unsigned int* hist = (unsigned int*)(ws + HIST_OFF);
    int* scal  = (int*)(ws + SCAL_OFF);
    float* S   = (float*)(ws + S_OFF);
    float* h   = (float*)(ws + H_OFF);
    float* hT  = (float*)(ws + HT_OFF);
    float* sq  = (float*)(ws + SQ_OFF);
    unsigned char* bytesA = (unsigned char*)(ws + BYTES_OFF);

    const int have_bytes = (ws_size >= WS_NEED) ? 1 : 0;  // constant per process

    mil_init<<<818, 256, 0, stream>>>((unsigned int*)d_ws);
    mil_cnn<<<4096, 256, 0, stream>>>(x, w1, b1, w2, b2, fcw, fcb, h, hT, sq);
    mil_colsum<<<50, 256, 0, stream>>>(hT, S);
    mil_hist<<<dim3(32, 32), 256, 0, stream>>>(hT, sq, hist, bytesA, have_bytes);
    mil_scan<<<1, 64, 0, stream>>>(hist, scal);
    if (have_bytes) {
        mil_agg_b<<<dim3(64, 8), 256, 0, stream>>>(h, bytesA, scal, agg, deg);
        mil_agg_r<<<dim3(64, 8), 256, 0, stream>>>(h, hT, sq, scal, agg, deg, 1);
    } else {
        mil_agg_r<<<dim3(64, 8), 256, 0, stream>>>(h, hT, sq, scal, agg, deg, 0);
    }
    mil_sage<<<820, 256, 0, stream>>>(h, agg, deg, S, scal, relw, relb, rootw, Xp);
    mil_final<<<1, 64, 0, stream>>>(Xp, scal, relw, relb, rootw,
                                    l1w, l1b, l2w, l2b, (float*)d_out);
}

// Round 9
// 538.782 us; speedup vs baseline: 1.1599x; 1.0031x over previous
//
#include <hip/hip_runtime.h>
#include <hip/hip_bf16.h>

// ---------------- workspace layout (bytes) ----------------
#define AGG_OFF     0u          // f32[4096*50]  (zeroed)
#define DEG_OFF     819200u     // f32[4096]     (zeroed)
#define XP_OFF      835584u     // f32[64]       (zeroed)
#define HIST_OFF    835840u     // u32[257]      (zeroed)
#define SCAL_OFF    836992u     // i32[8]        (zeroed; written by scan)
#define S_OFF       837120u     // f32[50] colsum of h
#define H_OFF       1048576u    // f32[4096][50] row-major
#define HT_OFF      1867776u    // f32[50][4096] transposed
#define SQ_OFF      2686976u    // f32[4096] row squared-norms
#define BYTES_OFF   2703360u    // u8[4096][4096] bucket bytes (optional)
#define WS_NEED     (2703360ull + 16777216ull)

// ============================================================
// Kernel 0: zero the accumulator region of the workspace
// ============================================================
__global__ __launch_bounds__(256) void mil_init(unsigned int* __restrict__ w)
{
    w[(size_t)blockIdx.x * 256u + threadIdx.x] = 0u;
}

// ============================================================
// Kernel 1: per-instance LeNet -> h[4096][50], hT[50][4096], sq[4096]
// Row-rolled convs; conv2 weights staged [cc][2][32] with XOR bank
// swizzle (k ^ ((cc&7)<<2)) -> shift-only staging math + float4 reads
// at 2-way (free) conflict. FMA order per accumulator identical to
// round-4 -> bitwise-same h.
// ============================================================
__global__ __launch_bounds__(256, 5) void mil_cnn(
    const float* __restrict__ x, const float* __restrict__ w1, const float* __restrict__ b1,
    const float* __restrict__ w2, const float* __restrict__ b2,
    const float* __restrict__ fcw, const float* __restrict__ fcb,
    float* __restrict__ hout, float* __restrict__ hT, float* __restrict__ sqout)
{
    __shared__ __align__(16) float pool1[20*144];
    __shared__ __align__(16) float pool2[800];
    __shared__ float b1s[20];
    __shared__ float b2s[64];
    __shared__ float hloc[64];
    __shared__ __align__(16) float ovl[3200]; // conv1: img[784]+w1s[500]; conv2: w2s[50][2][32] swizzled

    float* img = ovl;
    float* w1s = ovl + 784;
    float* w2s = ovl;

    const int n = blockIdx.x;
    const int t = threadIdx.x;

    const float* xin = x + (size_t)n * 784;
    for (int i = t; i < 784; i += 256) img[i] = xin[i];
    for (int i = t; i < 500; i += 256) w1s[i] = w1[i];
    if (t < 20) b1s[t] = b1[t];
    { int u = t - 32; if (u >= 0 && u < 50) b2s[u] = b2[u]; }
    __syncthreads();

    // ---- conv1 (5x5, 1->20) + relu + 2x2 maxpool -> pool1[20][12][12]
    if (t < 240) {
        const int c = t / 12, py = t % 12;
        float wr[25];
#pragma unroll
        for (int k = 0; k < 25; k++) wr[k] = w1s[c*25 + k];
        float acc0[24], acc1[24];
#pragma unroll
        for (int i = 0; i < 24; i++) { acc0[i] = 0.f; acc1[i] = 0.f; }
#pragma unroll
        for (int j = 0; j < 6; j++) {            // input rows 2py..2py+5, once each
            float rr[28];
            const float* rp = &img[(2*py + j)*28];   // 16B-aligned: 28%4==0
#pragma unroll
            for (int q = 0; q < 7; q++) {
                const float4 v = *(const float4*)(rp + 4*q);
                rr[4*q+0] = v.x; rr[4*q+1] = v.y; rr[4*q+2] = v.z; rr[4*q+3] = v.w;
            }
            if (j <= 4) {                         // out row 2py, tap ky=j
#pragma unroll
                for (int kx = 0; kx < 5; kx++) {
                    const float wv = wr[j*5 + kx];
#pragma unroll
                    for (int xo = 0; xo < 24; xo++)
                        acc0[xo] = fmaf(rr[xo+kx], wv, acc0[xo]);
                }
            }
            if (j >= 1) {                         // out row 2py+1, tap ky=j-1
#pragma unroll
                for (int kx = 0; kx < 5; kx++) {
                    const float wv = wr[(j-1)*5 + kx];
#pragma unroll
                    for (int xo = 0; xo < 24; xo++)
                        acc1[xo] = fmaf(rr[xo+kx], wv, acc1[xo]);
                }
            }
        }
        const float bias = b1s[c];
#pragma unroll
        for (int px = 0; px < 12; px++) {
            float v = fmaxf(fmaxf(acc0[2*px], acc0[2*px+1]),
                            fmaxf(acc1[2*px], acc1[2*px+1]));
            pool1[c*144 + py*12 + px] = fmaxf(v + bias, 0.f);
        }
    }
    __syncthreads();

    // ---- conv2 (5x5, 20->50) + relu + pool; 10 chunks of 2 input channels
    float acc2[16];
#pragma unroll
    for (int i = 0; i < 16; i++) acc2[i] = 0.f;
    const int c2 = t >> 2, py2 = t & 3;   // valid when t < 200
    const int rswz = (c2 & 7) << 2;       // read-side XOR swizzle
    for (int cig = 0; cig < 10; cig++) {
        __syncthreads();
        for (int idx = t; idx < 3200; idx += 256) {
            const int cc = idx >> 6, cl = (idx >> 5) & 1, k = idx & 31;
            const float v = (k < 25) ? w2[cc*500 + (cig*2 + cl)*25 + k] : 0.f;
            w2s[(idx & ~31) | (k ^ ((cc & 7) << 2))] = v;
        }
        __syncthreads();
        if (t < 200) {
#pragma unroll
            for (int cl = 0; cl < 2; cl++) {
                const int ci = cig*2 + cl;
                float wreg[25];
                const int wbase = c2*64 + cl*32;
#pragma unroll
                for (int g = 0; g < 6; g++) {
                    const float4 v = *(const float4*)&w2s[wbase + (4*g ^ rswz)];
                    wreg[4*g+0] = v.x; wreg[4*g+1] = v.y;
                    wreg[4*g+2] = v.z; wreg[4*g+3] = v.w;
                }
                wreg[24] = w2s[wbase + (24 ^ rswz)];
#pragma unroll
                for (int j = 0; j < 6; j++) {    // input rows 2py2..2py2+5, once
                    float rr[12];
                    const float* rp = &pool1[ci*144 + (2*py2 + j)*12]; // 16B-aligned
#pragma unroll
                    for (int q = 0; q < 3; q++) {
                        const float4 v = *(const float4*)(rp + 4*q);
                        rr[4*q+0] = v.x; rr[4*q+1] = v.y;
                        rr[4*q+2] = v.z; rr[4*q+3] = v.w;
                    }
                    if (j <= 4) {                 // out row 2py2, tap ky=j
#pragma unroll
                        for (int kx = 0; kx < 5; kx++) {
                            const float wv = wreg[j*5 + kx];
#pragma unroll
                            for (int xo = 0; xo < 8; xo++)
                                acc2[xo] = fmaf(rr[xo+kx], wv, acc2[xo]);
                        }
                    }
                    if (j >= 1) {                 // out row 2py2+1, tap ky=j-1
#pragma unroll
                        for (int kx = 0; kx < 5; kx++) {
                            const float wv = wreg[(j-1)*5 + kx];
#pragma unroll
                            for (int xo = 0; xo < 8; xo++)
                                acc2[8+xo] = fmaf(rr[xo+kx], wv, acc2[8+xo]);
                        }
                    }
                }
            }
        }
    }
    __syncthreads();
    if (t < 200) {
        const float bias = b2s[c2];
#pragma unroll
        for (int px = 0; px < 4; px++) {
            float v = fmaxf(fmaxf(acc2[2*px], acc2[2*px+1]),
                            fmaxf(acc2[8+2*px], acc2[8+2*px+1]));
            pool2[c2*16 + py2*4 + px] = fmaxf(v + bias, 0.f);
        }
    }
    __syncthreads();

    // ---- fc: one wave per o-slice
    {
        const int wv = t >> 6, lane = t & 63;
        for (int o = wv; o < 50; o += 4) {
            float acc = 0.f;
#pragma unroll
            for (int r = 0; r < 13; r++) {
                const int k = r*64 + lane;
                if (k < 800) acc = fmaf(fcw[o*800 + k], pool2[k], acc);
            }
#pragma unroll
            for (int off = 32; off > 0; off >>= 1) acc += __shfl_xor(acc, off);
            if (lane == 0) hloc[o] = fmaxf(acc + fcb[o], 0.f);
        }
    }
    __syncthreads();
    if (t < 50) {
        const float v = hloc[t];
        hout[(size_t)n*50 + t] = v;
        hT[(size_t)t*4096 + n] = v;
    }
    if (t < 64) {
        float s = (t < 50) ? hloc[t]*hloc[t] : 0.f;
#pragma unroll
        for (int off = 32; off > 0; off >>= 1) s += __shfl_xor(s, off);
        if (t == 0) sqout[n] = s;
    }
}

// ============================================================
// Kernel 1b: S[d] = sum_n h[n][d]
// ============================================================
__global__ __launch_bounds__(256) void mil_colsum(
    const float* __restrict__ hT, float* __restrict__ S)
{
    __shared__ float red[4];
    const int d = blockIdx.x, t = threadIdx.x;
    float s = 0.f;
    for (int nn = t; nn < 4096; nn += 256) s += hT[(size_t)d*4096 + nn];
#pragma unroll
    for (int off = 32; off > 0; off >>= 1) s += __shfl_xor(s, off);
    if ((t & 63) == 0) red[t >> 6] = s;
    __syncthreads();
    if (t == 0) S[d] = red[0] + red[1] + red[2] + red[3];
}

// ============================================================
// Kernel 2: pairwise distances -> histogram buckets + bucket bytes.
// Wave-aggregated histogram atomics: one atomic per distinct bucket
// per wave (buckets are concentrated -> few loop iterations).
// ============================================================
__global__ __launch_bounds__(256, 3) void mil_hist(
    const float* __restrict__ hT, const float* __restrict__ sq,
    unsigned int* __restrict__ hist, unsigned char* __restrict__ bytesA,
    const int wb)
{
    __shared__ __align__(16) float hiT[6400];   // [50][128]
    __shared__ __align__(16) float hjT[6400];
    __shared__ float sqi[128], sqj[128];
    __shared__ unsigned int lh[257];

    const int t = threadIdx.x;
    const int lane = t & 63;
    const int i0 = blockIdx.x * 128, j0 = blockIdx.y * 128;

    for (int idx = t; idx < 6400; idx += 256) {
        const int c = idx >> 7, l = idx & 127;
        hiT[idx] = hT[(size_t)c*4096 + i0 + l];
        hjT[idx] = hT[(size_t)c*4096 + j0 + l];
    }
    if (t < 128) { sqi[t] = sq[i0 + t]; sqj[t] = sq[j0 + t]; }
    for (int idx = t; idx < 257; idx += 256) lh[idx] = 0;
    __syncthreads();

    const int ti = t >> 4, tj = t & 15;
    float acc[8][8];
#pragma unroll
    for (int a = 0; a < 8; a++)
#pragma unroll
        for (int b = 0; b < 8; b++) acc[a][b] = 0.f;

    for (int c = 0; c < 50; c++) {
        const float4 a0 = *(const float4*)&hiT[c*128 + ti*8];
        const float4 a1 = *(const float4*)&hiT[c*128 + ti*8 + 4];
        const float4 b0 = *(const float4*)&hjT[c*128 + tj*8];
        const float4 b1 = *(const float4*)&hjT[c*128 + tj*8 + 4];
        const float aa[8] = {a0.x,a0.y,a0.z,a0.w,a1.x,a1.y,a1.z,a1.w};
        const float bb[8] = {b0.x,b0.y,b0.z,b0.w,b1.x,b1.y,b1.z,b1.w};
#pragma unroll
        for (int a = 0; a < 8; a++)
#pragma unroll
            for (int b = 0; b < 8; b++)
                acc[a][b] = fmaf(aa[a], bb[b], acc[a][b]);
    }

#pragma unroll
    for (int a = 0; a < 8; a++) {
        unsigned pk0 = 0, pk1 = 0;
#pragma unroll
        for (int b = 0; b < 8; b++) {
            const int gi = i0 + ti*8 + a, gj = j0 + tj*8 + b;
            int kb = -1;
            int kbyte = 255;
            if (gi != gj) {
                const float d2 = sqi[ti*8+a] + sqj[tj*8+b] - 2.f*acc[a][b];
                const float d = sqrtf(fmaxf(d2, 0.f));
                int k = (int)floorf((d - 3.5f)*2.f) + 1;
                k = k < 0 ? 0 : (k > 256 ? 256 : k);
                if (k > 0   && d <  3.5f + 0.5f*(float)(k-1)) k--;
                if (k < 256 && d >= 3.5f + 0.5f*(float)k)     k++;
                kb = k;
                kbyte = k < 255 ? k : 255;
            }
            // wave-aggregated histogram update: one atomic per distinct bucket
            unsigned long long act = __ballot(kb >= 0);
            while (act) {
                const int src = __ffsll(act) - 1;
                const int kk = __shfl(kb, src);
                const unsigned long long same = __ballot(kb == kk) & act;
                if (lane == src) atomicAdd(&lh[kk], (unsigned)__popcll(same));
                act &= ~same;
            }
            if (b < 4) pk0 |= (unsigned)kbyte << (8*b);
            else       pk1 |= (unsigned)kbyte << (8*(b-4));
        }
        if (wb) {
            const int gi = i0 + ti*8 + a;
            *(uint2*)&bytesA[(size_t)gi*4096 + j0 + tj*8] = make_uint2(pk0, pk1);
        }
    }
    __syncthreads();
    for (int idx = t; idx < 257; idx += 256)
        if (lh[idx]) atomicAdd(&hist[idx], lh[idx]);
}

// ============================================================
// Kernel 3: prefix-scan -> kc, nnz, complement flag, byte-fallback flag
// ============================================================
__global__ void mil_scan(const unsigned int* __restrict__ hist, int* __restrict__ scal)
{
    if (threadIdx.x == 0) {
        unsigned long long cum = 0, nz = 0;
        int kc = -1;
        for (int k = 0; k < 256; k++) {
            cum += hist[k];
            if (kc < 0 && cum >= 410ull) { kc = k; nz = cum; }  // ceil(0.1*4096)
        }
        if (kc < 0) { kc = 0; nz = hist[0]; }
        scal[0] = kc;
        scal[1] = (int)nz;
        scal[2] = (nz * 2ull > 16773120ull) ? 1 : 0;   // complement if >half dense
        scal[3] = (kc >= 255) ? 1 : 0;                 // byte path ambiguous
    }
}

// ============================================================
// Kernel 4a: byte-driven aggregate (no gram recompute).
// ============================================================
__global__ __launch_bounds__(256) void mil_agg_b(
    const float* __restrict__ h, const unsigned char* __restrict__ bytesA,
    const int* __restrict__ scal, float* __restrict__ agg, float* __restrict__ deg)
{
    __shared__ __align__(16) unsigned char bL[64*528];
    __shared__ __align__(16) float hsub[4096];      // [jj][d], d padded to 64
    if (scal[3] != 0) return;                        // fallback kernel handles
    const int t = threadIdx.x;
    const int i0 = blockIdx.x * 64;
    const int jg = blockIdx.y * 512;
    const int kc = scal[0];
    const bool inv = (scal[2] != 0);

    for (int idx = t; idx < 2048; idx += 256) {
        const int r = idx >> 5, c = idx & 31;
        *(uint4*)&bL[r*528 + c*16] =
            *(const uint4*)&bytesA[(size_t)(i0 + r)*4096 + jg + c*16];
    }

    const int il = t >> 2, dq = t & 3;
    const int gi = i0 + il;
    float accum[16];
#pragma unroll
    for (int i = 0; i < 16; i++) accum[i] = 0.f;
    int degc = 0;

    for (int js = 0; js < 8; js++) {
        __syncthreads();
        for (int idx = t; idx < 4096; idx += 256) {
            const int jj = idx >> 6, d = idx & 63;
            hsub[idx] = (d < 50) ? h[(size_t)(jg + js*64 + jj)*50 + d] : 0.f;
        }
        __syncthreads();
        const unsigned char* brow = &bL[il*528 + js*64];
        const int jbase = jg + js*64;
        for (int jj = 0; jj < 64; jj++) {
            const bool e = (jbase + jj != gi) && ((brow[jj] <= kc) != inv);
            if (!__any(e)) continue;          // fast path: whole-wave skip
            const float m = e ? 1.f : 0.f;
            if (e && dq == 0) degc++;
#pragma unroll
            for (int q = 0; q < 4; q++) {
                const float4 hv = *(const float4*)&hsub[jj*64 + dq*16 + q*4];
                accum[q*4+0] = fmaf(m, hv.x, accum[q*4+0]);
                accum[q*4+1] = fmaf(m, hv.y, accum[q*4+1]);
                accum[q*4+2] = fmaf(m, hv.z, accum[q*4+2]);
                accum[q*4+3] = fmaf(m, hv.w, accum[q*4+3]);
            }
        }
    }

#pragma unroll
    for (int q = 0; q < 4; q++)
#pragma unroll
        for (int rr = 0; rr < 4; rr++) {
            const int d = dq*16 + q*4 + rr;
            if (d < 50 && accum[q*4+rr] != 0.f)
                atomicAdd(&agg[(size_t)gi*50 + d], accum[q*4+rr]);
        }
    if (dq == 0 && degc) atomicAdd(&deg[gi], (float)degc);
}

// ============================================================
// Kernel 4b: recompute-gram aggregate (fallback)
// ============================================================
__global__ __launch_bounds__(256, 3) void mil_agg_r(
    const float* __restrict__ h, const float* __restrict__ hT, const float* __restrict__ sq,
    const int* __restrict__ scal, float* __restrict__ agg, float* __restrict__ deg,
    const int mode)
{
    __shared__ __align__(16) float hiT[3200];       // [50][64]
    __shared__ __align__(16) float hjT[3200];
    __shared__ float sqi[64], sqj[64];
    __shared__ __align__(16) float hsub[4096];
    __shared__ __align__(16) unsigned char mk[4096];

    if (mode == 1 && scal[3] == 0) return;   // byte kernel handled it
    const int t = threadIdx.x;
    const int i0 = blockIdx.x * 64;
    const float thr = 3.5f + 0.5f * (float)scal[0];
    const bool inv = (scal[2] != 0);

    for (int idx = t; idx < 3200; idx += 256) {
        const int c = idx >> 6, l = idx & 63;
        hiT[idx] = hT[(size_t)c*4096 + i0 + l];
    }
    if (t < 64) sqi[t] = sq[i0 + t];

    const int ti = t >> 4, tj = t & 15;
    const int il = t >> 2, dq = t & 3;
    float accum[16];
#pragma unroll
    for (int i = 0; i < 16; i++) accum[i] = 0.f;
    int degc = 0;

    for (int js = 0; js < 8; js++) {
        const int j0 = blockIdx.y * 512 + js * 64;
        __syncthreads();
        for (int idx = t; idx < 3200; idx += 256) {
            const int c = idx >> 6, l = idx & 63;
            hjT[idx] = hT[(size_t)c*4096 + j0 + l];
        }
        for (int idx = t; idx < 4096; idx += 256) {
            const int jj = idx >> 6, d = idx & 63;
            hsub[idx] = (d < 50) ? h[(size_t)(j0 + jj)*50 + d] : 0.f;
        }
        if (t < 64) sqj[t] = sq[j0 + t];
        __syncthreads();

        float acc[4][4];
#pragma unroll
        for (int a = 0; a < 4; a++)
#pragma unroll
            for (int b = 0; b < 4; b++) acc[a][b] = 0.f;
        for (int c = 0; c < 50; c++) {
            const float4 av = *(const float4*)&hiT[c*64 + ti*4];
            const float4 bv = *(const float4*)&hjT[c*64 + tj*4];
            const float aa[4] = {av.x, av.y, av.z, av.w};
            const float bb[4] = {bv.x, bv.y, bv.z, bv.w};
#pragma unroll
            for (int a = 0; a < 4; a++)
#pragma unroll
                for (int b = 0; b < 4; b++)
                    acc[a][b] = fmaf(aa[a], bb[b], acc[a][b]);
        }

#pragma unroll
        for (int b = 0; b < 4; b++) {
            unsigned char ob[4];
#pragma unroll
            for (int a = 0; a < 4; a++) {
                const int gi = i0 + ti*4 + a, gj = j0 + tj*4 + b;
                const float d2 = sqi[ti*4+a] + sqj[tj*4+b] - 2.f*acc[a][b];
                const float dd = sqrtf(fmaxf(d2, 0.f));
                const bool edge = (dd < thr);
                ob[a] = (gi != gj && (edge != inv)) ? 1 : 0;
            }
            *(uchar4*)&mk[(tj*4+b)*64 + ti*4] = make_uchar4(ob[0], ob[1], ob[2], ob[3]);
        }
        __syncthreads();

        for (int jj = 0; jj < 64; jj++) {
            const bool e = (mk[jj*64 + il] != 0);
            if (!__any(e)) continue;
            const float m = e ? 1.f : 0.f;
            if (e && dq == 0) degc++;
#pragma unroll
            for (int q = 0; q < 4; q++) {
                const float4 hv = *(const float4*)&hsub[jj*64 + dq*16 + q*4];
                accum[q*4+0] = fmaf(m, hv.x, accum[q*4+0]);
                accum[q*4+1] = fmaf(m, hv.y, accum[q*4+1]);
                accum[q*4+2] = fmaf(m, hv.z, accum[q*4+2]);
                accum[q*4+3] = fmaf(m, hv.w, accum[q*4+3]);
            }
        }
    }

    const int node = i0 + il;
#pragma unroll
    for (int q = 0; q < 4; q++)
#pragma unroll
        for (int rr = 0; rr < 4; rr++) {
            const int d = dq*16 + q*4 + rr;
            if (d < 50 && accum[q*4+rr] != 0.f)
                atomicAdd(&agg[(size_t)node*50 + d], accum[q*4+rr]);
        }
    if (dq == 0 && degc) atomicAdd(&deg[node], (float)degc);
}

// ============================================================
// Kernel 5: Z = leaky(mean-agg@relW^T + relb + h@rootW^T); Xp += colsum(Z)
// ============================================================
__global__ __launch_bounds__(256) void mil_sage(
    const float* __restrict__ h, const float* __restrict__ agg, const float* __restrict__ deg,
    const float* __restrict__ S, const int* __restrict__ scal,
    const float* __restrict__ relw, const float* __restrict__ relb,
    const float* __restrict__ rootw, float* __restrict__ Xp)
{
    __shared__ float relT[2500];   // [c][d]
    __shared__ float rootT[2500];
    __shared__ float rb[50];
    __shared__ float hn[250], mn[250], zb[250];
    const int t = threadIdx.x;
    const int nb = blockIdx.x * 5;
    const bool inv = (scal[2] != 0);

    for (int idx = t; idx < 2500; idx += 256) {
        const int d = idx / 50, c = idx % 50;
        relT[c*50 + d]  = relw[idx];
        rootT[c*50 + d] = rootw[idx];
    }
    if (t < 50) rb[t] = relb[t];
    if (t < 250) {
        const int nl = t / 50, d = t % 50;
        const int node = nb + nl;
        if (node < 4096) {
            const float hv = h[(size_t)node*50 + d];
            float av = agg[(size_t)node*50 + d];
            float dg = deg[node];
            if (inv) { av = S[d] - hv - av; dg = 4095.f - dg; }
            hn[t] = hv;
            mn[t] = av / fmaxf(dg, 1.f);
        } else { hn[t] = 0.f; mn[t] = 0.f; }
    }
    __syncthreads();
    if (t < 250) {
        const int nl = t / 50, d = t % 50;
        float z = rb[d];
        for (int c = 0; c < 50; c++) {
            z = fmaf(mn[nl*50 + c], relT[c*50 + d], z);
            z = fmaf(hn[nl*50 + c], rootT[c*50 + d], z);
        }
        z = z > 0.f ? z : 0.01f * z;
        zb[t] = (nb + nl < 4096) ? z : 0.f;
    }
    __syncthreads();
    if (t < 50) {
        float s = 0.f;
#pragma unroll
        for (int nl = 0; nl < 5; nl++) s += zb[nl*50 + t];
        atomicAdd(&Xp[t], s);
    }
}

// ============================================================
// Kernel 6: pooled sage + lin1 + lin2 + softmax -> out[3] (f32)
// ============================================================
__global__ void mil_final(
    const float* __restrict__ Xp, const int* __restrict__ scal,
    const float* __restrict__ relw, const float* __restrict__ relb,
    const float* __restrict__ rootw,
    const float* __restrict__ l1w, const float* __restrict__ l1b,
    const float* __restrict__ l2w, const float* __restrict__ l2b,
    float* __restrict__ out)
{
    __shared__ float xp[50], x2[50], v1[25], v2[2];
    const int t = threadIdx.x;
    if (t < 50) xp[t] = Xp[t];
    __syncthreads();
    const float adjp = (float)scal[1];
    const float dmax = fmaxf(adjp, 1.f);
    if (t < 50) {
        float z = relb[t];
        for (int c = 0; c < 50; c++) {
            const float mnc = (adjp * xp[c]) / dmax;
            z = fmaf(mnc,   relw[t*50 + c], z);
            z = fmaf(xp[c], rootw[t*50 + c], z);
        }
        x2[t] = z > 0.f ? z : 0.01f*z;
    }
    __syncthreads();
    if (t < 25) {
        float v = l1b[t];
        for (int c = 0; c < 50; c++) v = fmaf(l1w[t*50 + c], x2[c], v);
        v1[t] = v > 0.f ? v : 0.01f*v;
    }
    __syncthreads();
    if (t < 2) {
        float v = l2b[t];
        for (int c = 0; c < 25; c++) v = fmaf(l2w[t*25 + c], v1[c], v);
        v2[t] = v > 0.f ? v : 0.01f*v;
    }
    __syncthreads();
    if (t == 0) {
        const float a = v2[0], b = v2[1];
        const float mx = fmaxf(a, b);
        const float e0 = expf(a - mx), e1 = expf(b - mx);
        const float s = e0 + e1;
        const float p0 = e0 / s, p1 = e1 / s;
        const float pm = fmaxf(p0, p1);
        const float am = (p1 > p0) ? 1.f : 0.f;
        const int nnz = scal[1];
        const float l1v = sqrtf((float)(16777216 - nnz)) / 16777216.f;
        out[0] = pm;
        out[1] = am;
        out[2] = l1v;
    }
}

// ============================================================
extern "C" void kernel_launch(void* const* d_in, const int* in_sizes, int n_in,
                              void* d_out, int out_size, void* d_ws, size_t ws_size,
                              hipStream_t stream)
{
    (void)in_sizes; (void)n_in; (void)out_size;
    const float* x     = (const float*)d_in[0];
    const float* w1    = (const float*)d_in[1];
    const float* b1    = (const float*)d_in[2];
    const float* w2    = (const float*)d_in[3];
    const float* b2    = (const float*)d_in[4];
    const float* fcw   = (const float*)d_in[5];
    const float* fcb   = (const float*)d_in[6];
    const float* relw  = (const float*)d_in[7];
    const float* relb  = (const float*)d_in[8];
    const float* rootw = (const float*)d_in[9];
    // d_in[10..14] (pool_*, mlp_*) are dead: softmax over a length-1 axis == 1
    const float* l1w   = (const float*)d_in[15];
    const float* l1b   = (const float*)d_in[16];
    const float* l2w   = (const float*)d_in[17];
    const float* l2b   = (const float*)d_in[18];

    char* ws = (char*)d_ws;
    float* agg = (float*)(ws + AGG_OFF);
    float* deg = (float*)(ws + DEG_OFF);
    float* Xp  = (float*)(ws + XP_OFF);
    unsigned int* hist = (unsigned int*)(ws + HIST_OFF);
    int* scal  = (int*)(ws + SCAL_OFF);
    float* S   = (float*)(ws + S_OFF);
    float* h   = (float*)(ws + H_OFF);
    float* hT  = (float*)(ws + HT_OFF);
    float* sq  = (float*)(ws + SQ_OFF);
    unsigned char* bytesA = (unsigned char*)(ws + BYTES_OFF);

    const int have_bytes = (ws_size >= WS_NEED) ? 1 : 0;  // constant per process

    mil_init<<<818, 256, 0, stream>>>((unsigned int*)d_ws);
    mil_cnn<<<4096, 256, 0, stream>>>(x, w1, b1, w2, b2, fcw, fcb, h, hT, sq);
    mil_colsum<<<50, 256, 0, stream>>>(hT, S);
    mil_hist<<<dim3(32, 32), 256, 0, stream>>>(hT, sq, hist, bytesA, have_bytes);
    mil_scan<<<1, 64, 0, stream>>>(hist, scal);
    if (have_bytes) {
        mil_agg_b<<<dim3(64, 8), 256, 0, stream>>>(h, bytesA, scal, agg, deg);
        mil_agg_r<<<dim3(64, 8), 256, 0, stream>>>(h, hT, sq, scal, agg, deg, 1);
    } else {
        mil_agg_r<<<dim3(64, 8), 256, 0, stream>>>(h, hT, sq, scal, agg, deg, 0);
    }
    mil_sage<<<820, 256, 0, stream>>>(h, agg, deg, S, scal, relw, relb, rootw, Xp);
    mil_final<<<1, 64, 0, stream>>>(Xp, scal, relw, relb, rootw,
                                    l1w, l1b, l2w, l2b, (float*)d_out);
}

// Round 11
// 528.596 us; speedup vs baseline: 1.1823x; 1.0193x over previous
//
#include <hip/hip_runtime.h>
#include <hip/hip_bf16.h>

// ---------------- workspace layout (bytes) ----------------
#define AGG_OFF     0u          // f32[4096*50]  (zeroed)
#define DEG_OFF     819200u     // f32[4096]     (zeroed)
#define XP_OFF      835584u     // f32[64]       (zeroed)
#define HIST_OFF    835840u     // u32[257]      (zeroed)
#define SCAL_OFF    836992u     // i32[8]        (zeroed; written by scan)
#define S_OFF       837120u     // f32[50] colsum of h
#define H_OFF       1048576u    // f32[4096][50] row-major
#define HT_OFF      1867776u    // f32[50][4096] transposed
#define SQ_OFF      2686976u    // f32[4096] row squared-norms
#define BYTES_OFF   2703360u    // u8[4096][4096] bucket bytes (optional)
#define WS_NEED     (2703360ull + 16777216ull)

// ============================================================
// Kernel 0: zero the accumulator region of the workspace
// ============================================================
__global__ __launch_bounds__(256) void mil_init(unsigned int* __restrict__ w)
{
    w[(size_t)blockIdx.x * 256u + threadIdx.x] = 0u;
}

// ============================================================
// Kernel 1: per-instance LeNet -> h[4096][50], hT[50][4096], sq[4096]
// launch_bounds(256,4): 128-VGPR cap so conv1's ~101-reg live set and
// conv2's wreg/acc/rr fit without rematerialization (at (256,5) the
// allocator squeezed to 48 VGPR -> ~135us of extra VALU issue).
// FMA order per accumulator identical to round-4 -> bitwise-same h.
// ============================================================
__global__ __launch_bounds__(256, 4) void mil_cnn(
    const float* __restrict__ x, const float* __restrict__ w1, const float* __restrict__ b1,
    const float* __restrict__ w2, const float* __restrict__ b2,
    const float* __restrict__ fcw, const float* __restrict__ fcb,
    float* __restrict__ hout, float* __restrict__ hT, float* __restrict__ sqout)
{
    __shared__ __align__(16) float pool1[20*144];
    __shared__ __align__(16) float pool2[800];
    __shared__ float b1s[20];
    __shared__ float b2s[64];
    __shared__ float hloc[64];
    __shared__ __align__(16) float ovl[3200]; // conv1: img[784]+w1s[500]; conv2: w2s[50][2][32] swizzled

    float* img = ovl;
    float* w1s = ovl + 784;
    float* w2s = ovl;

    const int n = blockIdx.x;
    const int t = threadIdx.x;

    const float* xin = x + (size_t)n * 784;
    for (int i = t; i < 784; i += 256) img[i] = xin[i];
    for (int i = t; i < 500; i += 256) w1s[i] = w1[i];
    if (t < 20) b1s[t] = b1[t];
    { int u = t - 32; if (u >= 0 && u < 50) b2s[u] = b2[u]; }
    __syncthreads();

    // ---- conv1 (5x5, 1->20) + relu + 2x2 maxpool -> pool1[20][12][12]
    if (t < 240) {
        const int c = t / 12, py = t % 12;
        float wr[25];
#pragma unroll
        for (int k = 0; k < 25; k++) wr[k] = w1s[c*25 + k];
        float acc0[24], acc1[24];
#pragma unroll
        for (int i = 0; i < 24; i++) { acc0[i] = 0.f; acc1[i] = 0.f; }
#pragma unroll
        for (int j = 0; j < 6; j++) {            // input rows 2py..2py+5, once each
            float rr[28];
            const float* rp = &img[(2*py + j)*28];   // 16B-aligned: 28%4==0
#pragma unroll
            for (int q = 0; q < 7; q++) {
                const float4 v = *(const float4*)(rp + 4*q);
                rr[4*q+0] = v.x; rr[4*q+1] = v.y; rr[4*q+2] = v.z; rr[4*q+3] = v.w;
            }
            if (j <= 4) {                         // out row 2py, tap ky=j
#pragma unroll
                for (int kx = 0; kx < 5; kx++) {
                    const float wv = wr[j*5 + kx];
#pragma unroll
                    for (int xo = 0; xo < 24; xo++)
                        acc0[xo] = fmaf(rr[xo+kx], wv, acc0[xo]);
                }
            }
            if (j >= 1) {                         // out row 2py+1, tap ky=j-1
#pragma unroll
                for (int kx = 0; kx < 5; kx++) {
                    const float wv = wr[(j-1)*5 + kx];
#pragma unroll
                    for (int xo = 0; xo < 24; xo++)
                        acc1[xo] = fmaf(rr[xo+kx], wv, acc1[xo]);
                }
            }
        }
        const float bias = b1s[c];
#pragma unroll
        for (int px = 0; px < 12; px++) {
            float v = fmaxf(fmaxf(acc0[2*px], acc0[2*px+1]),
                            fmaxf(acc1[2*px], acc1[2*px+1]));
            pool1[c*144 + py*12 + px] = fmaxf(v + bias, 0.f);
        }
    }
    __syncthreads();

    // ---- conv2 (5x5, 20->50) + relu + pool; 10 chunks of 2 input channels
    float acc2[16];
#pragma unroll
    for (int i = 0; i < 16; i++) acc2[i] = 0.f;
    const int c2 = t >> 2, py2 = t & 3;   // valid when t < 200
    const int rswz = (c2 & 7) << 2;       // read-side XOR swizzle
    for (int cig = 0; cig < 10; cig++) {
        __syncthreads();
        for (int idx = t; idx < 3200; idx += 256) {
            const int cc = idx >> 6, cl = (idx >> 5) & 1, k = idx & 31;
            const float v = (k < 25) ? w2[cc*500 + (cig*2 + cl)*25 + k] : 0.f;
            w2s[(idx & ~31) | (k ^ ((cc & 7) << 2))] = v;
        }
        __syncthreads();
        if (t < 200) {
#pragma unroll
            for (int cl = 0; cl < 2; cl++) {
                const int ci = cig*2 + cl;
                float wreg[25];
                const int wbase = c2*64 + cl*32;
#pragma unroll
                for (int g = 0; g < 6; g++) {
                    const float4 v = *(const float4*)&w2s[wbase + (4*g ^ rswz)];
                    wreg[4*g+0] = v.x; wreg[4*g+1] = v.y;
                    wreg[4*g+2] = v.z; wreg[4*g+3] = v.w;
                }
                wreg[24] = w2s[wbase + (24 ^ rswz)];
#pragma unroll
                for (int j = 0; j < 6; j++) {    // input rows 2py2..2py2+5, once
                    float rr[12];
                    const float* rp = &pool1[ci*144 + (2*py2 + j)*12]; // 16B-aligned
#pragma unroll
                    for (int q = 0; q < 3; q++) {
                        const float4 v = *(const float4*)(rp + 4*q);
                        rr[4*q+0] = v.x; rr[4*q+1] = v.y;
                        rr[4*q+2] = v.z; rr[4*q+3] = v.w;
                    }
                    if (j <= 4) {                 // out row 2py2, tap ky=j
#pragma unroll
                        for (int kx = 0; kx < 5; kx++) {
                            const float wv = wreg[j*5 + kx];
#pragma unroll
                            for (int xo = 0; xo < 8; xo++)
                                acc2[xo] = fmaf(rr[xo+kx], wv, acc2[xo]);
                        }
                    }
                    if (j >= 1) {                 // out row 2py2+1, tap ky=j-1
#pragma unroll
                        for (int kx = 0; kx < 5; kx++) {
                            const float wv = wreg[(j-1)*5 + kx];
#pragma unroll
                            for (int xo = 0; xo < 8; xo++)
                                acc2[8+xo] = fmaf(rr[xo+kx], wv, acc2[8+xo]);
                        }
                    }
                }
            }
        }
    }
    __syncthreads();
    if (t < 200) {
        const float bias = b2s[c2];
#pragma unroll
        for (int px = 0; px < 4; px++) {
            float v = fmaxf(fmaxf(acc2[2*px], acc2[2*px+1]),
                            fmaxf(acc2[8+2*px], acc2[8+2*px+1]));
            pool2[c2*16 + py2*4 + px] = fmaxf(v + bias, 0.f);
        }
    }
    __syncthreads();

    // ---- fc: one wave per o-slice
    {
        const int wv = t >> 6, lane = t & 63;
        for (int o = wv; o < 50; o += 4) {
            float acc = 0.f;
#pragma unroll
            for (int r = 0; r < 13; r++) {
                const int k = r*64 + lane;
                if (k < 800) acc = fmaf(fcw[o*800 + k], pool2[k], acc);
            }
#pragma unroll
            for (int off = 32; off > 0; off >>= 1) acc += __shfl_xor(acc, off);
            if (lane == 0) hloc[o] = fmaxf(acc + fcb[o], 0.f);
        }
    }
    __syncthreads();
    if (t < 50) {
        const float v = hloc[t];
        hout[(size_t)n*50 + t] = v;
        hT[(size_t)t*4096 + n] = v;
    }
    if (t < 64) {
        float s = (t < 50) ? hloc[t]*hloc[t] : 0.f;
#pragma unroll
        for (int off = 32; off > 0; off >>= 1) s += __shfl_xor(s, off);
        if (t == 0) sqout[n] = s;
    }
}

// ============================================================
// Kernel 1b: S[d] = sum_n h[n][d]
// ============================================================
__global__ __launch_bounds__(256) void mil_colsum(
    const float* __restrict__ hT, float* __restrict__ S)
{
    __shared__ float red[4];
    const int d = blockIdx.x, t = threadIdx.x;
    float s = 0.f;
    for (int nn = t; nn < 4096; nn += 256) s += hT[(size_t)d*4096 + nn];
#pragma unroll
    for (int off = 32; off > 0; off >>= 1) s += __shfl_xor(s, off);
    if ((t & 63) == 0) red[t >> 6] = s;
    __syncthreads();
    if (t == 0) S[d] = red[0] + red[1] + red[2] + red[3];
}

// ============================================================
// Kernel 2: pairwise distances -> histogram buckets + bucket bytes.
// Per-pair LDS atomics (round-8 proven; ballot aggregation regressed).
// ============================================================
__global__ __launch_bounds__(256, 3) void mil_hist(
    const float* __restrict__ hT, const float* __restrict__ sq,
    unsigned int* __restrict__ hist, unsigned char* __restrict__ bytesA,
    const int wb)
{
    __shared__ __align__(16) float hiT[6400];   // [50][128]
    __shared__ __align__(16) float hjT[6400];
    __shared__ float sqi[128], sqj[128];
    __shared__ unsigned int lh[257];

    const int t = threadIdx.x;
    const int i0 = blockIdx.x * 128, j0 = blockIdx.y * 128;

    for (int idx = t; idx < 6400; idx += 256) {
        const int c = idx >> 7, l = idx & 127;
        hiT[idx] = hT[(size_t)c*4096 + i0 + l];
        hjT[idx] = hT[(size_t)c*4096 + j0 + l];
    }
    if (t < 128) { sqi[t] = sq[i0 + t]; sqj[t] = sq[j0 + t]; }
    for (int idx = t; idx < 257; idx += 256) lh[idx] = 0;
    __syncthreads();

    const int ti = t >> 4, tj = t & 15;
    float acc[8][8];
#pragma unroll
    for (int a = 0; a < 8; a++)
#pragma unroll
        for (int b = 0; b < 8; b++) acc[a][b] = 0.f;

    for (int c = 0; c < 50; c++) {
        const float4 a0 = *(const float4*)&hiT[c*128 + ti*8];
        const float4 a1 = *(const float4*)&hiT[c*128 + ti*8 + 4];
        const float4 b0 = *(const float4*)&hjT[c*128 + tj*8];
        const float4 b1 = *(const float4*)&hjT[c*128 + tj*8 + 4];
        const float aa[8] = {a0.x,a0.y,a0.z,a0.w,a1.x,a1.y,a1.z,a1.w};
        const float bb[8] = {b0.x,b0.y,b0.z,b0.w,b1.x,b1.y,b1.z,b1.w};
#pragma unroll
        for (int a = 0; a < 8; a++)
#pragma unroll
            for (int b = 0; b < 8; b++)
                acc[a][b] = fmaf(aa[a], bb[b], acc[a][b]);
    }

    unsigned int cnt0 = 0;
#pragma unroll
    for (int a = 0; a < 8; a++) {
        unsigned pk0 = 0, pk1 = 0;
#pragma unroll
        for (int b = 0; b < 8; b++) {
            const int gi = i0 + ti*8 + a, gj = j0 + tj*8 + b;
            int kbyte = 255;
            if (gi != gj) {
                const float d2 = sqi[ti*8+a] + sqj[tj*8+b] - 2.f*acc[a][b];
                const float d = sqrtf(fmaxf(d2, 0.f));
                int k = (int)floorf((d - 3.5f)*2.f) + 1;
                k = k < 0 ? 0 : (k > 256 ? 256 : k);
                if (k > 0   && d <  3.5f + 0.5f*(float)(k-1)) k--;
                if (k < 256 && d >= 3.5f + 0.5f*(float)k)     k++;
                if (k == 0) cnt0++;
                else atomicAdd(&lh[k], 1u);
                kbyte = k < 255 ? k : 255;
            }
            if (b < 4) pk0 |= (unsigned)kbyte << (8*b);
            else       pk1 |= (unsigned)kbyte << (8*(b-4));
        }
        if (wb) {
            const int gi = i0 + ti*8 + a;
            *(uint2*)&bytesA[(size_t)gi*4096 + j0 + tj*8] = make_uint2(pk0, pk1);
        }
    }
#pragma unroll
    for (int off = 32; off > 0; off >>= 1) cnt0 += __shfl_xor(cnt0, off);
    if ((t & 63) == 0 && cnt0) atomicAdd(&lh[0], cnt0);
    __syncthreads();
    for (int idx = t; idx < 257; idx += 256)
        if (lh[idx]) atomicAdd(&hist[idx], lh[idx]);
}

// ============================================================
// Kernel 3: prefix-scan -> kc, nnz, complement flag, byte-fallback flag
// ============================================================
__global__ void mil_scan(const unsigned int* __restrict__ hist, int* __restrict__ scal)
{
    if (threadIdx.x == 0) {
        unsigned long long cum = 0, nz = 0;
        int kc = -1;
        for (int k = 0; k < 256; k++) {
            cum += hist[k];
            if (kc < 0 && cum >= 410ull) { kc = k; nz = cum; }  // ceil(0.1*4096)
        }
        if (kc < 0) { kc = 0; nz = hist[0]; }
        scal[0] = kc;
        scal[1] = (int)nz;
        scal[2] = (nz * 2ull > 16773120ull) ? 1 : 0;   // complement if >half dense
        scal[3] = (kc >= 255) ? 1 : 0;                 // byte path ambiguous
    }
}

// ============================================================
// Kernel 4a: byte-driven aggregate (no gram recompute).
// ============================================================
__global__ __launch_bounds__(256) void mil_agg_b(
    const float* __restrict__ h, const unsigned char* __restrict__ bytesA,
    const int* __restrict__ scal, float* __restrict__ agg, float* __restrict__ deg)
{
    __shared__ __align__(16) unsigned char bL[64*528];
    __shared__ __align__(16) float hsub[4096];      // [jj][d], d padded to 64
    if (scal[3] != 0) return;                        // fallback kernel handles
    const int t = threadIdx.x;
    const int i0 = blockIdx.x * 64;
    const int jg = blockIdx.y * 512;
    const int kc = scal[0];
    const bool inv = (scal[2] != 0);

    for (int idx = t; idx < 2048; idx += 256) {
        const int r = idx >> 5, c = idx & 31;
        *(uint4*)&bL[r*528 + c*16] =
            *(const uint4*)&bytesA[(size_t)(i0 + r)*4096 + jg + c*16];
    }

    const int il = t >> 2, dq = t & 3;
    const int gi = i0 + il;
    float accum[16];
#pragma unroll
    for (int i = 0; i < 16; i++) accum[i] = 0.f;
    int degc = 0;

    for (int js = 0; js < 8; js++) {
        __syncthreads();
        for (int idx = t; idx < 4096; idx += 256) {
            const int jj = idx >> 6, d = idx & 63;
            hsub[idx] = (d < 50) ? h[(size_t)(jg + js*64 + jj)*50 + d] : 0.f;
        }
        __syncthreads();
        const unsigned char* brow = &bL[il*528 + js*64];
        const int jbase = jg + js*64;
        for (int jj = 0; jj < 64; jj++) {
            const bool e = (jbase + jj != gi) && ((brow[jj] <= kc) != inv);
            if (!__any(e)) continue;          // fast path: whole-wave skip
            const float m = e ? 1.f : 0.f;
            if (e && dq == 0) degc++;
#pragma unroll
            for (int q = 0; q < 4; q++) {
                const float4 hv = *(const float4*)&hsub[jj*64 + dq*16 + q*4];
                accum[q*4+0] = fmaf(m, hv.x, accum[q*4+0]);
                accum[q*4+1] = fmaf(m, hv.y, accum[q*4+1]);
                accum[q*4+2] = fmaf(m, hv.z, accum[q*4+2]);
                accum[q*4+3] = fmaf(m, hv.w, accum[q*4+3]);
            }
        }
    }

#pragma unroll
    for (int q = 0; q < 4; q++)
#pragma unroll
        for (int rr = 0; rr < 4; rr++) {
            const int d = dq*16 + q*4 + rr;
            if (d < 50 && accum[q*4+rr] != 0.f)
                atomicAdd(&agg[(size_t)gi*50 + d], accum[q*4+rr]);
        }
    if (dq == 0 && degc) atomicAdd(&deg[gi], (float)degc);
}

// ============================================================
// Kernel 4b: recompute-gram aggregate (fallback)
// ============================================================
__global__ __launch_bounds__(256, 3) void mil_agg_r(
    const float* __restrict__ h, const float* __restrict__ hT, const float* __restrict__ sq,
    const int* __restrict__ scal, float* __restrict__ agg, float* __restrict__ deg,
    const int mode)
{
    __shared__ __align__(16) float hiT[3200];       // [50][64]
    __shared__ __align__(16) float hjT[3200];
    __shared__ float sqi[64], sqj[64];
    __shared__ __align__(16) float hsub[4096];
    __shared__ __align__(16) unsigned char mk[4096];

    if (mode == 1 && scal[3] == 0) return;   // byte kernel handled it
    const int t = threadIdx.x;
    const int i0 = blockIdx.x * 64;
    const float thr = 3.5f + 0.5f * (float)scal[0];
    const bool inv = (scal[2] != 0);

    for (int idx = t; idx < 3200; idx += 256) {
        const int c = idx >> 6, l = idx & 63;
        hiT[idx] = hT[(size_t)c*4096 + i0 + l];
    }
    if (t < 64) sqi[t] = sq[i0 + t];

    const int ti = t >> 4, tj = t & 15;
    const int il = t >> 2, dq = t & 3;
    float accum[16];
#pragma unroll
    for (int i = 0; i < 16; i++) accum[i] = 0.f;
    int degc = 0;

    for (int js = 0; js < 8; js++) {
        const int j0 = blockIdx.y * 512 + js * 64;
        __syncthreads();
        for (int idx = t; idx < 3200; idx += 256) {
            const int c = idx >> 6, l = idx & 63;
            hjT[idx] = hT[(size_t)c*4096 + j0 + l];
        }
        for (int idx = t; idx < 4096; idx += 256) {
            const int jj = idx >> 6, d = idx & 63;
            hsub[idx] = (d < 50) ? h[(size_t)(j0 + jj)*50 + d] : 0.f;
        }
        if (t < 64) sqj[t] = sq[j0 + t];
        __syncthreads();

        float acc[4][4];
#pragma unroll
        for (int a = 0; a < 4; a++)
#pragma unroll
            for (int b = 0; b < 4; b++) acc[a][b] = 0.f;
        for (int c = 0; c < 50; c++) {
            const float4 av = *(const float4*)&hiT[c*64 + ti*4];
            const float4 bv = *(const float4*)&hjT[c*64 + tj*4];
            const float aa[4] = {av.x, av.y, av.z, av.w};
            const float bb[4] = {bv.x, bv.y, bv.z, bv.w};
#pragma unroll
            for (int a = 0; a < 4; a++)
#pragma unroll
                for (int b = 0; b < 4; b++)
                    acc[a][b] = fmaf(aa[a], bb[b], acc[a][b]);
        }

#pragma unroll
        for (int b = 0; b < 4; b++) {
            unsigned char ob[4];
#pragma unroll
            for (int a = 0; a < 4; a++) {
                const int gi = i0 + ti*4 + a, gj = j0 + tj*4 + b;
                const float d2 = sqi[ti*4+a] + sqj[tj*4+b] - 2.f*acc[a][b];
                const float dd = sqrtf(fmaxf(d2, 0.f));
                const bool edge = (dd < thr);
                ob[a] = (gi != gj && (edge != inv)) ? 1 : 0;
            }
            *(uchar4*)&mk[(tj*4+b)*64 + ti*4] = make_uchar4(ob[0], ob[1], ob[2], ob[3]);
        }
        __syncthreads();

        for (int jj = 0; jj < 64; jj++) {
            const bool e = (mk[jj*64 + il] != 0);
            if (!__any(e)) continue;
            const float m = e ? 1.f : 0.f;
            if (e && dq == 0) degc++;
#pragma unroll
            for (int q = 0; q < 4; q++) {
                const float4 hv = *(const float4*)&hsub[jj*64 + dq*16 + q*4];
                accum[q*4+0] = fmaf(m, hv.x, accum[q*4+0]);
                accum[q*4+1] = fmaf(m, hv.y, accum[q*4+1]);
                accum[q*4+2] = fmaf(m, hv.z, accum[q*4+2]);
                accum[q*4+3] = fmaf(m, hv.w, accum[q*4+3]);
            }
        }
    }

    const int node = i0 + il;
#pragma unroll
    for (int q = 0; q < 4; q++)
#pragma unroll
        for (int rr = 0; rr < 4; rr++) {
            const int d = dq*16 + q*4 + rr;
            if (d < 50 && accum[q*4+rr] != 0.f)
                atomicAdd(&agg[(size_t)node*50 + d], accum[q*4+rr]);
        }
    if (dq == 0 && degc) atomicAdd(&deg[node], (float)degc);
}

// ============================================================
// Kernel 5: Z = leaky(mean-agg@relW^T + relb + h@rootW^T); Xp += colsum(Z)
// ============================================================
__global__ __launch_bounds__(256) void mil_sage(
    const float* __restrict__ h, const float* __restrict__ agg, const float* __restrict__ deg,
    const float* __restrict__ S, const int* __restrict__ scal,
    const float* __restrict__ relw, const float* __restrict__ relb,
    const float* __restrict__ rootw, float* __restrict__ Xp)
{
    __shared__ float relT[2500];   // [c][d]
    __shared__ float rootT[2500];
    __shared__ float rb[50];
    __shared__ float hn[250], mn[250], zb[250];
    const int t = threadIdx.x;
    const int nb = blockIdx.x * 5;
    const bool inv = (scal[2] != 0);

    for (int idx = t; idx < 2500; idx += 256) {
        const int d = idx / 50, c = idx % 50;
        relT[c*50 + d]  = relw[idx];
        rootT[c*50 + d] = rootw[idx];
    }
    if (t < 50) rb[t] = relb[t];
    if (t < 250) {
        const int nl = t / 50, d = t % 50;
        const int node = nb + nl;
        if (node < 4096) {
            const float hv = h[(size_t)node*50 + d];
            float av = agg[(size_t)node*50 + d];
            float dg = deg[node];
            if (inv) { av = S[d] - hv - av; dg = 4095.f - dg; }
            hn[t] = hv;
            mn[t] = av / fmaxf(dg, 1.f);
        } else { hn[t] = 0.f; mn[t] = 0.f; }
    }
    __syncthreads();
    if (t < 250) {
        const int nl = t / 50, d = t % 50;
        float z = rb[d];
        for (int c = 0; c < 50; c++) {
            z = fmaf(mn[nl*50 + c], relT[c*50 + d], z);
            z = fmaf(hn[nl*50 + c], rootT[c*50 + d], z);
        }
        z = z > 0.f ? z : 0.01f * z;
        zb[t] = (nb + nl < 4096) ? z : 0.f;
    }
    __syncthreads();
    if (t < 50) {
        float s = 0.f;
#pragma unroll
        for (int nl = 0; nl < 5; nl++) s += zb[nl*50 + t];
        atomicAdd(&Xp[t], s);
    }
}

// ============================================================
// Kernel 6: pooled sage + lin1 + lin2 + softmax -> out[3] (f32)
// ============================================================
__global__ void mil_final(
    const float* __restrict__ Xp, const int* __restrict__ scal,
    const float* __restrict__ relw, const float* __restrict__ relb,
    const float* __restrict__ rootw,
    const float* __restrict__ l1w, const float* __restrict__ l1b,
    const float* __restrict__ l2w, const float* __restrict__ l2b,
    float* __restrict__ out)
{
    __shared__ float xp[50], x2[50], v1[25], v2[2];
    const int t = threadIdx.x;
    if (t < 50) xp[t] = Xp[t];
    __syncthreads();
    const float adjp = (float)scal[1];
    const float dmax = fmaxf(adjp, 1.f);
    if (t < 50) {
        float z = relb[t];
        for (int c = 0; c < 50; c++) {
            const float mnc = (adjp * xp[c]) / dmax;
            z = fmaf(mnc,   relw[t*50 + c], z);
            z = fmaf(xp[c], rootw[t*50 + c], z);
        }
        x2[t] = z > 0.f ? z : 0.01f*z;
    }
    __syncthreads();
    if (t < 25) {
        float v = l1b[t];
        for (int c = 0; c < 50; c++) v = fmaf(l1w[t*50 + c], x2[c], v);
        v1[t] = v > 0.f ? v : 0.01f*v;
    }
    __syncthreads();
    if (t < 2) {
        float v = l2b[t];
        for (int c = 0; c < 25; c++) v = fmaf(l2w[t*25 + c], v1[c], v);
        v2[t] = v > 0.f ? v : 0.01f*v;
    }
    __syncthreads();
    if (t == 0) {
        const float a = v2[0], b = v2[1];
        const float mx = fmaxf(a, b);
        const float e0 = expf(a - mx), e1 = expf(b - mx);
        const float s = e0 + e1;
        const float p0 = e0 / s, p1 = e1 / s;
        const float pm = fmaxf(p0, p1);
        const float am = (p1 > p0) ? 1.f : 0.f;
        const int nnz = scal[1];
        const float l1v = sqrtf((float)(16777216 - nnz)) / 16777216.f;
        out[0] = pm;
        out[1] = am;
        out[2] = l1v;
    }
}

// ============================================================
extern "C" void kernel_launch(void* const* d_in, const int* in_sizes, int n_in,
                              void* d_out, int out_size, void* d_ws, size_t ws_size,
                              hipStream_t stream)
{
    (void)in_sizes; (void)n_in; (void)out_size;
    const float* x     = (const float*)d_in[0];
    const float* w1    = (const float*)d_in[1];
    const float* b1    = (const float*)d_in[2];
    const float* w2    = (const float*)d_in[3];
    const float* b2    = (const float*)d_in[4];
    const float* fcw   = (const float*)d_in[5];
    const float* fcb   = (const float*)d_in[6];
    const float* relw  = (const float*)d_in[7];
    const float* relb  = (const float*)d_in[8];
    const float* rootw = (const float*)d_in[9];
    // d_in[10..14] (pool_*, mlp_*) are dead: softmax over a length-1 axis == 1
    const float* l1w   = (const float*)d_in[15];
    const float* l1b   = (const float*)d_in[16];
    const float* l2w   = (const float*)d_in[17];
    const float* l2b   = (const float*)d_in[18];

    char* ws = (char*)d_ws;
    float* agg = (float*)(ws + AGG_OFF);
    float* deg = (float*)(ws + DEG_OFF);
    float* Xp  = (float*)(ws + XP_OFF);
    unsigned int* hist = (unsigned int*)(ws + HIST_OFF);
    int* scal  = (int*)(ws + SCAL_OFF);
    float* S   = (float*)(ws + S_OFF);
    float* h   = (float*)(ws + H_OFF);
    float* hT  = (float*)(ws + HT_OFF);
    float* sq  = (float*)(ws + SQ_OFF);
    unsigned char* bytesA = (unsigned char*)(ws + BYTES_OFF);

    const int have_bytes = (ws_size >= WS_NEED) ? 1 : 0;  // constant per process

    mil_init<<<818, 256, 0, stream>>>((unsigned int*)d_ws);
    mil_cnn<<<4096, 256, 0, stream>>>(x, w1, b1, w2, b2, fcw, fcb, h, hT, sq);
    mil_colsum<<<50, 256, 0, stream>>>(hT, S);
    mil_hist<<<dim3(32, 32), 256, 0, stream>>>(hT, sq, hist, bytesA, have_bytes);
    mil_scan<<<1, 64, 0, stream>>>(hist, scal);
    if (have_bytes) {
        mil_agg_b<<<dim3(64, 8), 256, 0, stream>>>(h, bytesA, scal, agg, deg);
        mil_agg_r<<<dim3(64, 8), 256, 0, stream>>>(h, hT, sq, scal, agg, deg, 1);
    } else {
        mil_agg_r<<<dim3(64, 8), 256, 0, stream>>>(h, hT, sq, scal, agg, deg, 0);
    }
    mil_sage<<<820, 256, 0, stream>>>(h, agg, deg, S, scal, relw, relb, rootw, Xp);
    mil_final<<<1, 64, 0, stream>>>(Xp, scal, relw, relb, rootw,
                                    l1w, l1b, l2w, l2b, (float*)d_out);
}

// Round 12
// 524.846 us; speedup vs baseline: 1.1907x; 1.0071x over previous
//
#include <hip/hip_runtime.h>
#include <hip/hip_bf16.h>

// ---------------- workspace layout (bytes) ----------------
#define AGG_OFF     0u          // f32[4096*50]  (zeroed)
#define DEG_OFF     819200u     // f32[4096]     (zeroed)
#define XP_OFF      835584u     // f32[64]       (zeroed)
#define HIST_OFF    835840u     // u32[257]      (zeroed)
#define SCAL_OFF    836992u     // i32[8]        (zeroed; written by scan)
#define S_OFF       837120u     // f32[50] colsum of h
#define H_OFF       1048576u    // f32[4096][50] row-major
#define HT_OFF      1867776u    // f32[50][4096] transposed
#define SQ_OFF      2686976u    // f32[4096] row squared-norms
#define BYTES_OFF   2703360u    // u8[4096][4096] bucket bytes (optional)
#define WS_NEED     (2703360ull + 16777216ull)

// ============================================================
// Kernel 0: zero the accumulator region of the workspace
// ============================================================
__global__ __launch_bounds__(256) void mil_init(unsigned int* __restrict__ w)
{
    w[(size_t)blockIdx.x * 256u + threadIdx.x] = 0u;
}

// ============================================================
// Kernel 1: per-instance LeNet -> h[4096][50], hT[50][4096], sq[4096]
// launch_bounds(256,2): VGPR cap 256 so the allocator stops squeezing
// to the 8-wave/SIMD step (52 regs) and can hold conv1's ~100-reg live
// set (acc0[24]+acc1[24]+weights+row window) without LDS re-reads.
// (256,4) still squeezed to 52 -> allocator targets occupancy steps,
// not the bound. FMA order identical to round-4 -> bitwise-same h.
// ============================================================
__global__ __launch_bounds__(256, 2) void mil_cnn(
    const float* __restrict__ x, const float* __restrict__ w1, const float* __restrict__ b1,
    const float* __restrict__ w2, const float* __restrict__ b2,
    const float* __restrict__ fcw, const float* __restrict__ fcb,
    float* __restrict__ hout, float* __restrict__ hT, float* __restrict__ sqout)
{
    __shared__ __align__(16) float pool1[20*144];
    __shared__ __align__(16) float pool2[800];
    __shared__ float b1s[20];
    __shared__ float b2s[64];
    __shared__ float hloc[64];
    __shared__ __align__(16) float ovl[3200]; // conv1: img[784]+w1s[500]; conv2: w2s[50][2][32] swizzled

    float* img = ovl;
    float* w1s = ovl + 784;
    float* w2s = ovl;

    const int n = blockIdx.x;
    const int t = threadIdx.x;

    const float* xin = x + (size_t)n * 784;
    for (int i = t; i < 784; i += 256) img[i] = xin[i];
    for (int i = t; i < 500; i += 256) w1s[i] = w1[i];
    if (t < 20) b1s[t] = b1[t];
    { int u = t - 32; if (u >= 0 && u < 50) b2s[u] = b2[u]; }
    __syncthreads();

    // ---- conv1 (5x5, 1->20) + relu + 2x2 maxpool -> pool1[20][12][12]
    if (t < 240) {
        const int c = t / 12, py = t % 12;
        float wr[25];
#pragma unroll
        for (int k = 0; k < 25; k++) wr[k] = w1s[c*25 + k];
        float acc0[24], acc1[24];
#pragma unroll
        for (int i = 0; i < 24; i++) { acc0[i] = 0.f; acc1[i] = 0.f; }
#pragma unroll
        for (int j = 0; j < 6; j++) {            // input rows 2py..2py+5, once each
            float rr[28];
            const float* rp = &img[(2*py + j)*28];   // 16B-aligned: 28%4==0
#pragma unroll
            for (int q = 0; q < 7; q++) {
                const float4 v = *(const float4*)(rp + 4*q);
                rr[4*q+0] = v.x; rr[4*q+1] = v.y; rr[4*q+2] = v.z; rr[4*q+3] = v.w;
            }
            if (j <= 4) {                         // out row 2py, tap ky=j
#pragma unroll
                for (int kx = 0; kx < 5; kx++) {
                    const float wv = wr[j*5 + kx];
#pragma unroll
                    for (int xo = 0; xo < 24; xo++)
                        acc0[xo] = fmaf(rr[xo+kx], wv, acc0[xo]);
                }
            }
            if (j >= 1) {                         // out row 2py+1, tap ky=j-1
#pragma unroll
                for (int kx = 0; kx < 5; kx++) {
                    const float wv = wr[(j-1)*5 + kx];
#pragma unroll
                    for (int xo = 0; xo < 24; xo++)
                        acc1[xo] = fmaf(rr[xo+kx], wv, acc1[xo]);
                }
            }
        }
        const float bias = b1s[c];
#pragma unroll
        for (int px = 0; px < 12; px++) {
            float v = fmaxf(fmaxf(acc0[2*px], acc0[2*px+1]),
                            fmaxf(acc1[2*px], acc1[2*px+1]));
            pool1[c*144 + py*12 + px] = fmaxf(v + bias, 0.f);
        }
    }
    __syncthreads();

    // ---- conv2 (5x5, 20->50) + relu + pool; 10 chunks of 2 input channels
    float acc2[16];
#pragma unroll
    for (int i = 0; i < 16; i++) acc2[i] = 0.f;
    const int c2 = t >> 2, py2 = t & 3;   // valid when t < 200
    const int rswz = (c2 & 7) << 2;       // read-side XOR swizzle
    for (int cig = 0; cig < 10; cig++) {
        __syncthreads();
        for (int idx = t; idx < 3200; idx += 256) {
            const int cc = idx >> 6, cl = (idx >> 5) & 1, k = idx & 31;
            const float v = (k < 25) ? w2[cc*500 + (cig*2 + cl)*25 + k] : 0.f;
            w2s[(idx & ~31) | (k ^ ((cc & 7) << 2))] = v;
        }
        __syncthreads();
        if (t < 200) {
#pragma unroll
            for (int cl = 0; cl < 2; cl++) {
                const int ci = cig*2 + cl;
                float wreg[25];
                const int wbase = c2*64 + cl*32;
#pragma unroll
                for (int g = 0; g < 6; g++) {
                    const float4 v = *(const float4*)&w2s[wbase + (4*g ^ rswz)];
                    wreg[4*g+0] = v.x; wreg[4*g+1] = v.y;
                    wreg[4*g+2] = v.z; wreg[4*g+3] = v.w;
                }
                wreg[24] = w2s[wbase + (24 ^ rswz)];
#pragma unroll
                for (int j = 0; j < 6; j++) {    // input rows 2py2..2py2+5, once
                    float rr[12];
                    const float* rp = &pool1[ci*144 + (2*py2 + j)*12]; // 16B-aligned
#pragma unroll
                    for (int q = 0; q < 3; q++) {
                        const float4 v = *(const float4*)(rp + 4*q);
                        rr[4*q+0] = v.x; rr[4*q+1] = v.y;
                        rr[4*q+2] = v.z; rr[4*q+3] = v.w;
                    }
                    if (j <= 4) {                 // out row 2py2, tap ky=j
#pragma unroll
                        for (int kx = 0; kx < 5; kx++) {
                            const float wv = wreg[j*5 + kx];
#pragma unroll
                            for (int xo = 0; xo < 8; xo++)
                                acc2[xo] = fmaf(rr[xo+kx], wv, acc2[xo]);
                        }
                    }
                    if (j >= 1) {                 // out row 2py2+1, tap ky=j-1
#pragma unroll
                        for (int kx = 0; kx < 5; kx++) {
                            const float wv = wreg[(j-1)*5 + kx];
#pragma unroll
                            for (int xo = 0; xo < 8; xo++)
                                acc2[8+xo] = fmaf(rr[xo+kx], wv, acc2[8+xo]);
                        }
                    }
                }
            }
        }
    }
    __syncthreads();
    if (t < 200) {
        const float bias = b2s[c2];
#pragma unroll
        for (int px = 0; px < 4; px++) {
            float v = fmaxf(fmaxf(acc2[2*px], acc2[2*px+1]),
                            fmaxf(acc2[8+2*px], acc2[8+2*px+1]));
            pool2[c2*16 + py2*4 + px] = fmaxf(v + bias, 0.f);
        }
    }
    __syncthreads();

    // ---- fc: one wave per o-slice
    {
        const int wv = t >> 6, lane = t & 63;
        for (int o = wv; o < 50; o += 4) {
            float acc = 0.f;
#pragma unroll
            for (int r = 0; r < 13; r++) {
                const int k = r*64 + lane;
                if (k < 800) acc = fmaf(fcw[o*800 + k], pool2[k], acc);
            }
#pragma unroll
            for (int off = 32; off > 0; off >>= 1) acc += __shfl_xor(acc, off);
            if (lane == 0) hloc[o] = fmaxf(acc + fcb[o], 0.f);
        }
    }
    __syncthreads();
    if (t < 50) {
        const float v = hloc[t];
        hout[(size_t)n*50 + t] = v;
        hT[(size_t)t*4096 + n] = v;
    }
    if (t < 64) {
        float s = (t < 50) ? hloc[t]*hloc[t] : 0.f;
#pragma unroll
        for (int off = 32; off > 0; off >>= 1) s += __shfl_xor(s, off);
        if (t == 0) sqout[n] = s;
    }
}

// ============================================================
// Kernel 1b: S[d] = sum_n h[n][d]
// ============================================================
__global__ __launch_bounds__(256) void mil_colsum(
    const float* __restrict__ hT, float* __restrict__ S)
{
    __shared__ float red[4];
    const int d = blockIdx.x, t = threadIdx.x;
    float s = 0.f;
    for (int nn = t; nn < 4096; nn += 256) s += hT[(size_t)d*4096 + nn];
#pragma unroll
    for (int off = 32; off > 0; off >>= 1) s += __shfl_xor(s, off);
    if ((t & 63) == 0) red[t >> 6] = s;
    __syncthreads();
    if (t == 0) S[d] = red[0] + red[1] + red[2] + red[3];
}

// ============================================================
// Kernel 2: pairwise distances -> histogram buckets + bucket bytes.
// Per-pair LDS atomics (round-8 proven; ballot aggregation regressed).
// ============================================================
__global__ __launch_bounds__(256, 3) void mil_hist(
    const float* __restrict__ hT, const float* __restrict__ sq,
    unsigned int* __restrict__ hist, unsigned char* __restrict__ bytesA,
    const int wb)
{
    __shared__ __align__(16) float hiT[6400];   // [50][128]
    __shared__ __align__(16) float hjT[6400];
    __shared__ float sqi[128], sqj[128];
    __shared__ unsigned int lh[257];

    const int t = threadIdx.x;
    const int i0 = blockIdx.x * 128, j0 = blockIdx.y * 128;

    for (int idx = t; idx < 6400; idx += 256) {
        const int c = idx >> 7, l = idx & 127;
        hiT[idx] = hT[(size_t)c*4096 + i0 + l];
        hjT[idx] = hT[(size_t)c*4096 + j0 + l];
    }
    if (t < 128) { sqi[t] = sq[i0 + t]; sqj[t] = sq[j0 + t]; }
    for (int idx = t; idx < 257; idx += 256) lh[idx] = 0;
    __syncthreads();

    const int ti = t >> 4, tj = t & 15;
    float acc[8][8];
#pragma unroll
    for (int a = 0; a < 8; a++)
#pragma unroll
        for (int b = 0; b < 8; b++) acc[a][b] = 0.f;

    for (int c = 0; c < 50; c++) {
        const float4 a0 = *(const float4*)&hiT[c*128 + ti*8];
        const float4 a1 = *(const float4*)&hiT[c*128 + ti*8 + 4];
        const float4 b0 = *(const float4*)&hjT[c*128 + tj*8];
        const float4 b1 = *(const float4*)&hjT[c*128 + tj*8 + 4];
        const float aa[8] = {a0.x,a0.y,a0.z,a0.w,a1.x,a1.y,a1.z,a1.w};
        const float bb[8] = {b0.x,b0.y,b0.z,b0.w,b1.x,b1.y,b1.z,b1.w};
#pragma unroll
        for (int a = 0; a < 8; a++)
#pragma unroll
            for (int b = 0; b < 8; b++)
                acc[a][b] = fmaf(aa[a], bb[b], acc[a][b]);
    }

    unsigned int cnt0 = 0;
#pragma unroll
    for (int a = 0; a < 8; a++) {
        unsigned pk0 = 0, pk1 = 0;
#pragma unroll
        for (int b = 0; b < 8; b++) {
            const int gi = i0 + ti*8 + a, gj = j0 + tj*8 + b;
            int kbyte = 255;
            if (gi != gj) {
                const float d2 = sqi[ti*8+a] + sqj[tj*8+b] - 2.f*acc[a][b];
                const float d = sqrtf(fmaxf(d2, 0.f));
                int k = (int)floorf((d - 3.5f)*2.f) + 1;
                k = k < 0 ? 0 : (k > 256 ? 256 : k);
                if (k > 0   && d <  3.5f + 0.5f*(float)(k-1)) k--;
                if (k < 256 && d >= 3.5f + 0.5f*(float)k)     k++;
                if (k == 0) cnt0++;
                else atomicAdd(&lh[k], 1u);
                kbyte = k < 255 ? k : 255;
            }
            if (b < 4) pk0 |= (unsigned)kbyte << (8*b);
            else       pk1 |= (unsigned)kbyte << (8*(b-4));
        }
        if (wb) {
            const int gi = i0 + ti*8 + a;
            *(uint2*)&bytesA[(size_t)gi*4096 + j0 + tj*8] = make_uint2(pk0, pk1);
        }
    }
#pragma unroll
    for (int off = 32; off > 0; off >>= 1) cnt0 += __shfl_xor(cnt0, off);
    if ((t & 63) == 0 && cnt0) atomicAdd(&lh[0], cnt0);
    __syncthreads();
    for (int idx = t; idx < 257; idx += 256)
        if (lh[idx]) atomicAdd(&hist[idx], lh[idx]);
}

// ============================================================
// Kernel 3: prefix-scan -> kc, nnz, complement flag, byte-fallback flag
// ============================================================
__global__ void mil_scan(const unsigned int* __restrict__ hist, int* __restrict__ scal)
{
    if (threadIdx.x == 0) {
        unsigned long long cum = 0, nz = 0;
        int kc = -1;
        for (int k = 0; k < 256; k++) {
            cum += hist[k];
            if (kc < 0 && cum >= 410ull) { kc = k; nz = cum; }  // ceil(0.1*4096)
        }
        if (kc < 0) { kc = 0; nz = hist[0]; }
        scal[0] = kc;
        scal[1] = (int)nz;
        scal[2] = (nz * 2ull > 16773120ull) ? 1 : 0;   // complement if >half dense
        scal[3] = (kc >= 255) ? 1 : 0;                 // byte path ambiguous
    }
}

// ============================================================
// Kernel 4a: byte-driven aggregate (no gram recompute).
// ============================================================
__global__ __launch_bounds__(256) void mil_agg_b(
    const float* __restrict__ h, const unsigned char* __restrict__ bytesA,
    const int* __restrict__ scal, float* __restrict__ agg, float* __restrict__ deg)
{
    __shared__ __align__(16) unsigned char bL[64*528];
    __shared__ __align__(16) float hsub[4096];      // [jj][d], d padded to 64
    if (scal[3] != 0) return;                        // fallback kernel handles
    const int t = threadIdx.x;
    const int i0 = blockIdx.x * 64;
    const int jg = blockIdx.y * 512;
    const int kc = scal[0];
    const bool inv = (scal[2] != 0);

    for (int idx = t; idx < 2048; idx += 256) {
        const int r = idx >> 5, c = idx & 31;
        *(uint4*)&bL[r*528 + c*16] =
            *(const uint4*)&bytesA[(size_t)(i0 + r)*4096 + jg + c*16];
    }

    const int il = t >> 2, dq = t & 3;
    const int gi = i0 + il;
    float accum[16];
#pragma unroll
    for (int i = 0; i < 16; i++) accum[i] = 0.f;
    int degc = 0;

    for (int js = 0; js < 8; js++) {
        __syncthreads();
        for (int idx = t; idx < 4096; idx += 256) {
            const int jj = idx >> 6, d = idx & 63;
            hsub[idx] = (d < 50) ? h[(size_t)(jg + js*64 + jj)*50 + d] : 0.f;
        }
        __syncthreads();
        const unsigned char* brow = &bL[il*528 + js*64];
        const int jbase = jg + js*64;
        for (int jj = 0; jj < 64; jj++) {
            const bool e = (jbase + jj != gi) && ((brow[jj] <= kc) != inv);
            if (!__any(e)) continue;          // fast path: whole-wave skip
            const float m = e ? 1.f : 0.f;
            if (e && dq == 0) degc++;
#pragma unroll
            for (int q = 0; q < 4; q++) {
                const float4 hv = *(const float4*)&hsub[jj*64 + dq*16 + q*4];
                accum[q*4+0] = fmaf(m, hv.x, accum[q*4+0]);
                accum[q*4+1] = fmaf(m, hv.y, accum[q*4+1]);
                accum[q*4+2] = fmaf(m, hv.z, accum[q*4+2]);
                accum[q*4+3] = fmaf(m, hv.w, accum[q*4+3]);
            }
        }
    }

#pragma unroll
    for (int q = 0; q < 4; q++)
#pragma unroll
        for (int rr = 0; rr < 4; rr++) {
            const int d = dq*16 + q*4 + rr;
            if (d < 50 && accum[q*4+rr] != 0.f)
                atomicAdd(&agg[(size_t)gi*50 + d], accum[q*4+rr]);
        }
    if (dq == 0 && degc) atomicAdd(&deg[gi], (float)degc);
}

// ============================================================
// Kernel 4b: recompute-gram aggregate (fallback)
// ============================================================
__global__ __launch_bounds__(256, 3) void mil_agg_r(
    const float* __restrict__ h, const float* __restrict__ hT, const float* __restrict__ sq,
    const int* __restrict__ scal, float* __restrict__ agg, float* __restrict__ deg,
    const int mode)
{
    __shared__ __align__(16) float hiT[3200];       // [50][64]
    __shared__ __align__(16) float hjT[3200];
    __shared__ float sqi[64], sqj[64];
    __shared__ __align__(16) float hsub[4096];
    __shared__ __align__(16) unsigned char mk[4096];

    if (mode == 1 && scal[3] == 0) return;   // byte kernel handled it
    const int t = threadIdx.x;
    const int i0 = blockIdx.x * 64;
    const float thr = 3.5f + 0.5f * (float)scal[0];
    const bool inv = (scal[2] != 0);

    for (int idx = t; idx < 3200; idx += 256) {
        const int c = idx >> 6, l = idx & 63;
        hiT[idx] = hT[(size_t)c*4096 + i0 + l];
    }
    if (t < 64) sqi[t] = sq[i0 + t];

    const int ti = t >> 4, tj = t & 15;
    const int il = t >> 2, dq = t & 3;
    float accum[16];
#pragma unroll
    for (int i = 0; i < 16; i++) accum[i] = 0.f;
    int degc = 0;

    for (int js = 0; js < 8; js++) {
        const int j0 = blockIdx.y * 512 + js * 64;
        __syncthreads();
        for (int idx = t; idx < 3200; idx += 256) {
            const int c = idx >> 6, l = idx & 63;
            hjT[idx] = hT[(size_t)c*4096 + j0 + l];
        }
        for (int idx = t; idx < 4096; idx += 256) {
            const int jj = idx >> 6, d = idx & 63;
            hsub[idx] = (d < 50) ? h[(size_t)(j0 + jj)*50 + d] : 0.f;
        }
        if (t < 64) sqj[t] = sq[j0 + t];
        __syncthreads();

        float acc[4][4];
#pragma unroll
        for (int a = 0; a < 4; a++)
#pragma unroll
            for (int b = 0; b < 4; b++) acc[a][b] = 0.f;
        for (int c = 0; c < 50; c++) {
            const float4 av = *(const float4*)&hiT[c*64 + ti*4];
            const float4 bv = *(const float4*)&hjT[c*64 + tj*4];
            const float aa[4] = {av.x, av.y, av.z, av.w};
            const float bb[4] = {bv.x, bv.y, bv.z, bv.w};
#pragma unroll
            for (int a = 0; a < 4; a++)
#pragma unroll
                for (int b = 0; b < 4; b++)
                    acc[a][b] = fmaf(aa[a], bb[b], acc[a][b]);
        }

#pragma unroll
        for (int b = 0; b < 4; b++) {
            unsigned char ob[4];
#pragma unroll
            for (int a = 0; a < 4; a++) {
                const int gi = i0 + ti*4 + a, gj = j0 + tj*4 + b;
                const float d2 = sqi[ti*4+a] + sqj[tj*4+b] - 2.f*acc[a][b];
                const float dd = sqrtf(fmaxf(d2, 0.f));
                const bool edge = (dd < thr);
                ob[a] = (gi != gj && (edge != inv)) ? 1 : 0;
            }
            *(uchar4*)&mk[(tj*4+b)*64 + ti*4] = make_uchar4(ob[0], ob[1], ob[2], ob[3]);
        }
        __syncthreads();

        for (int jj = 0; jj < 64; jj++) {
            const bool e = (mk[jj*64 + il] != 0);
            if (!__any(e)) continue;
            const float m = e ? 1.f : 0.f;
            if (e && dq == 0) degc++;
#pragma unroll
            for (int q = 0; q < 4; q++) {
                const float4 hv = *(const float4*)&hsub[jj*64 + dq*16 + q*4];
                accum[q*4+0] = fmaf(m, hv.x, accum[q*4+0]);
                accum[q*4+1] = fmaf(m, hv.y, accum[q*4+1]);
                accum[q*4+2] = fmaf(m, hv.z, accum[q*4+2]);
                accum[q*4+3] = fmaf(m, hv.w, accum[q*4+3]);
            }
        }
    }

    const int node = i0 + il;
#pragma unroll
    for (int q = 0; q < 4; q++)
#pragma unroll
        for (int rr = 0; rr < 4; rr++) {
            const int d = dq*16 + q*4 + rr;
            if (d < 50 && accum[q*4+rr] != 0.f)
                atomicAdd(&agg[(size_t)node*50 + d], accum[q*4+rr]);
        }
    if (dq == 0 && degc) atomicAdd(&deg[node], (float)degc);
}

// ============================================================
// Kernel 5: Z = leaky(mean-agg@relW^T + relb + h@rootW^T); Xp += colsum(Z)
// ============================================================
__global__ __launch_bounds__(256) void mil_sage(
    const float* __restrict__ h, const float* __restrict__ agg, const float* __restrict__ deg,
    const float* __restrict__ S, const int* __restrict__ scal,
    const float* __restrict__ relw, const float* __restrict__ relb,
    const float* __restrict__ rootw, float* __restrict__ Xp)
{
    __shared__ float relT[2500];   // [c][d]
    __shared__ float rootT[2500];
    __shared__ float rb[50];
    __shared__ float hn[250], mn[250], zb[250];
    const int t = threadIdx.x;
    const int nb = blockIdx.x * 5;
    const bool inv = (scal[2] != 0);

    for (int idx = t; idx < 2500; idx += 256) {
        const int d = idx / 50, c = idx % 50;
        relT[c*50 + d]  = relw[idx];
        rootT[c*50 + d] = rootw[idx];
    }
    if (t < 50) rb[t] = relb[t];
    if (t < 250) {
        const int nl = t / 50, d = t % 50;
        const int node = nb + nl;
        if (node < 4096) {
            const float hv = h[(size_t)node*50 + d];
            float av = agg[(size_t)node*50 + d];
            float dg = deg[node];
            if (inv) { av = S[d] - hv - av; dg = 4095.f - dg; }
            hn[t] = hv;
            mn[t] = av / fmaxf(dg, 1.f);
        } else { hn[t] = 0.f; mn[t] = 0.f; }
    }
    __syncthreads();
    if (t < 250) {
        const int nl = t / 50, d = t % 50;
        float z = rb[d];
        for (int c = 0; c < 50; c++) {
            z = fmaf(mn[nl*50 + c], relT[c*50 + d], z);
            z = fmaf(hn[nl*50 + c], rootT[c*50 + d], z);
        }
        z = z > 0.f ? z : 0.01f * z;
        zb[t] = (nb + nl < 4096) ? z : 0.f;
    }
    __syncthreads();
    if (t < 50) {
        float s = 0.f;
#pragma unroll
        for (int nl = 0; nl < 5; nl++) s += zb[nl*50 + t];
        atomicAdd(&Xp[t], s);
    }
}

// ============================================================
// Kernel 6: pooled sage + lin1 + lin2 + softmax -> out[3] (f32)
// ============================================================
__global__ void mil_final(
    const float* __restrict__ Xp, const int* __restrict__ scal,
    const float* __restrict__ relw, const float* __restrict__ relb,
    const float* __restrict__ rootw,
    const float* __restrict__ l1w, const float* __restrict__ l1b,
    const float* __restrict__ l2w, const float* __restrict__ l2b,
    float* __restrict__ out)
{
    __shared__ float xp[50], x2[50], v1[25], v2[2];
    const int t = threadIdx.x;
    if (t < 50) xp[t] = Xp[t];
    __syncthreads();
    const float adjp = (float)scal[1];
    const float dmax = fmaxf(adjp, 1.f);
    if (t < 50) {
        float z = relb[t];
        for (int c = 0; c < 50; c++) {
            const float mnc = (adjp * xp[c]) / dmax;
            z = fmaf(mnc,   relw[t*50 + c], z);
            z = fmaf(xp[c], rootw[t*50 + c], z);
        }
        x2[t] = z > 0.f ? z : 0.01f*z;
    }
    __syncthreads();
    if (t < 25) {
        float v = l1b[t];
        for (int c = 0; c < 50; c++) v = fmaf(l1w[t*50 + c], x2[c], v);
        v1[t] = v > 0.f ? v : 0.01f*v;
    }
    __syncthreads();
    if (t < 2) {
        float v = l2b[t];
        for (int c = 0; c < 25; c++) v = fmaf(l2w[t*25 + c], v1[c], v);
        v2[t] = v > 0.f ? v : 0.01f*v;
    }
    __syncthreads();
    if (t == 0) {
        const float a = v2[0], b = v2[1];
        const float mx = fmaxf(a, b);
        const float e0 = expf(a - mx), e1 = expf(b - mx);
        const float s = e0 + e1;
        const float p0 = e0 / s, p1 = e1 / s;
        const float pm = fmaxf(p0, p1);
        const float am = (p1 > p0) ? 1.f : 0.f;
        const int nnz = scal[1];
        const float l1v = sqrtf((float)(16777216 - nnz)) / 16777216.f;
        out[0] = pm;
        out[1] = am;
        out[2] = l1v;
    }
}

// ============================================================
extern "C" void kernel_launch(void* const* d_in, const int* in_sizes, int n_in,
                              void* d_out, int out_size, void* d_ws, size_t ws_size,
                              hipStream_t stream)
{
    (void)in_sizes; (void)n_in; (void)out_size;
    const float* x     = (const float*)d_in[0];
    const float* w1    = (const float*)d_in[1];
    const float* b1    = (const float*)d_in[2];
    const float* w2    = (const float*)d_in[3];
    const float* b2    = (const float*)d_in[4];
    const float* fcw   = (const float*)d_in[5];
    const float* fcb   = (const float*)d_in[6];
    const float* relw  = (const float*)d_in[7];
    const float* relb  = (const float*)d_in[8];
    const float* rootw = (const float*)d_in[9];
    // d_in[10..14] (pool_*, mlp_*) are dead: softmax over a length-1 axis == 1
    const float* l1w   = (const float*)d_in[15];
    const float* l1b   = (const float*)d_in[16];
    const float* l2w   = (const float*)d_in[17];
    const float* l2b   = (const float*)d_in[18];

    char* ws = (char*)d_ws;
    float* agg = (float*)(ws + AGG_OFF);
    float* deg = (float*)(ws + DEG_OFF);
    float* Xp  = (float*)(ws + XP_OFF);
    unsigned int* hist = (unsigned int*)(ws + HIST_OFF);
    int* scal  = (int*)(ws + SCAL_OFF);
    float* S   = (float*)(ws + S_OFF);
    float* h   = (float*)(ws + H_OFF);
    float* hT  = (float*)(ws + HT_OFF);
    float* sq  = (float*)(ws + SQ_OFF);
    unsigned char* bytesA = (unsigned char*)(ws + BYTES_OFF);

    const int have_bytes = (ws_size >= WS_NEED) ? 1 : 0;  // constant per process

    mil_init<<<818, 256, 0, stream>>>((unsigned int*)d_ws);
    mil_cnn<<<4096, 256, 0, stream>>>(x, w1, b1, w2, b2, fcw, fcb, h, hT, sq);
    mil_colsum<<<50, 256, 0, stream>>>(hT, S);
    mil_hist<<<dim3(32, 32), 256, 0, stream>>>(hT, sq, hist, bytesA, have_bytes);
    mil_scan<<<1, 64, 0, stream>>>(hist, scal);
    if (have_bytes) {
        mil_agg_b<<<dim3(64, 8), 256, 0, stream>>>(h, bytesA, scal, agg, deg);
        mil_agg_r<<<dim3(64, 8), 256, 0, stream>>>(h, hT, sq, scal, agg, deg, 1);
    } else {
        mil_agg_r<<<dim3(64, 8), 256, 0, stream>>>(h, hT, sq, scal, agg, deg, 0);
    }
    mil_sage<<<820, 256, 0, stream>>>(h, agg, deg, S, scal, relw, relb, rootw, Xp);
    mil_final<<<1, 64, 0, stream>>>(Xp, scal, relw, relb, rootw,
                                    l1w, l1b, l2w, l2b, (float*)d_out);
}

// Round 13
// 493.849 us; speedup vs baseline: 1.2654x; 1.0628x over previous
//
#include <hip/hip_runtime.h>
#include <hip/hip_bf16.h>

// ---------------- workspace layout (bytes) ----------------
#define AGG_OFF     0u          // f32[4096*50]  (zeroed)
#define DEG_OFF     819200u     // f32[4096]     (zeroed)
#define XP_OFF      835584u     // f32[64]       (zeroed)
#define HIST_OFF    835840u     // u32[257]      (zeroed)
#define SCAL_OFF    836992u     // i32[8]        (zeroed; written by scan)
#define S_OFF       837120u     // f32[50] colsum of h
#define W2P_OFF     839680u     // f32[50][20][28] padded w2 (112000 B)
#define H_OFF       1048576u    // f32[4096][50] row-major
#define HT_OFF      1867776u    // f32[50][4096] transposed
#define SQ_OFF      2686976u    // f32[4096] row squared-norms
#define BYTES_OFF   2703360u    // u8[4096][4096] bucket bytes (optional)
#define WS_NEED     (2703360ull + 16777216ull)

// ============================================================
// Kernel 0: zero the accumulator region of the workspace
// ============================================================
__global__ __launch_bounds__(256) void mil_init(unsigned int* __restrict__ w)
{
    w[(size_t)blockIdx.x * 256u + threadIdx.x] = 0u;
}

// ============================================================
// Kernel 0b: pad w2 -> [50][20][28] (16B-aligned rows, zero-padded)
// ============================================================
__global__ __launch_bounds__(256) void mil_wpad(
    const float* __restrict__ w2, float* __restrict__ w2p)
{
    const int gid = blockIdx.x * 256 + threadIdx.x;   // < 28160
    if (gid < 28000) {
        const int k = gid % 28, rest = gid / 28;      // rest = c*20+ci
        w2p[gid] = (k < 25) ? w2[rest*25 + k] : 0.f;
    }
}

// ============================================================
// Kernel 1: per-instance LeNet -> h[4096][50], hT[50][4096], sq[4096]
// conv2 weights read DIRECTLY from global (L2-resident 112KB padded
// copy) -> no w2 LDS staging, no 20 per-block barriers. FMA order per
// accumulator identical to round-4 -> bitwise-same h.
// ============================================================
__global__ __launch_bounds__(256, 2) void mil_cnn(
    const float* __restrict__ x, const float* __restrict__ w1, const float* __restrict__ b1,
    const float* __restrict__ w2p, const float* __restrict__ b2,
    const float* __restrict__ fcw, const float* __restrict__ fcb,
    float* __restrict__ hout, float* __restrict__ hT, float* __restrict__ sqout)
{
    __shared__ __align__(16) float pool1[20*144];
    __shared__ __align__(16) float pool2[800];
    __shared__ __align__(16) float img[784];
    __shared__ float w1s[500];
    __shared__ float b1s[20];
    __shared__ float b2s[64];
    __shared__ float hloc[64];

    const int n = blockIdx.x;
    const int t = threadIdx.x;

    const float* xin = x + (size_t)n * 784;
    for (int i = t; i < 784; i += 256) img[i] = xin[i];
    for (int i = t; i < 500; i += 256) w1s[i] = w1[i];
    if (t < 20) b1s[t] = b1[t];
    { int u = t - 32; if (u >= 0 && u < 50) b2s[u] = b2[u]; }
    __syncthreads();

    // ---- conv1 (5x5, 1->20) + relu + 2x2 maxpool -> pool1[20][12][12]
    if (t < 240) {
        const int c = t / 12, py = t % 12;
        float wr[25];
#pragma unroll
        for (int k = 0; k < 25; k++) wr[k] = w1s[c*25 + k];
        float acc0[24], acc1[24];
#pragma unroll
        for (int i = 0; i < 24; i++) { acc0[i] = 0.f; acc1[i] = 0.f; }
#pragma unroll
        for (int j = 0; j < 6; j++) {            // input rows 2py..2py+5, once each
            float rr[28];
            const float* rp = &img[(2*py + j)*28];   // 16B-aligned: 28%4==0
#pragma unroll
            for (int q = 0; q < 7; q++) {
                const float4 v = *(const float4*)(rp + 4*q);
                rr[4*q+0] = v.x; rr[4*q+1] = v.y; rr[4*q+2] = v.z; rr[4*q+3] = v.w;
            }
            if (j <= 4) {                         // out row 2py, tap ky=j
#pragma unroll
                for (int kx = 0; kx < 5; kx++) {
                    const float wv = wr[j*5 + kx];
#pragma unroll
                    for (int xo = 0; xo < 24; xo++)
                        acc0[xo] = fmaf(rr[xo+kx], wv, acc0[xo]);
                }
            }
            if (j >= 1) {                         // out row 2py+1, tap ky=j-1
#pragma unroll
                for (int kx = 0; kx < 5; kx++) {
                    const float wv = wr[(j-1)*5 + kx];
#pragma unroll
                    for (int xo = 0; xo < 24; xo++)
                        acc1[xo] = fmaf(rr[xo+kx], wv, acc1[xo]);
                }
            }
        }
        const float bias = b1s[c];
#pragma unroll
        for (int px = 0; px < 12; px++) {
            float v = fmaxf(fmaxf(acc0[2*px], acc0[2*px+1]),
                            fmaxf(acc1[2*px], acc1[2*px+1]));
            pool1[c*144 + py*12 + px] = fmaxf(v + bias, 0.f);
        }
    }
    __syncthreads();

    // ---- conv2 (5x5, 20->50) + relu + pool; weights direct from global
    float acc2[16];
#pragma unroll
    for (int i = 0; i < 16; i++) acc2[i] = 0.f;
    const int c2 = t >> 2, py2 = t & 3;   // valid when t < 200
    if (t < 200) {
        const float* wch = w2p + c2*560;          // [20][28], 16B-aligned rows
        for (int ci = 0; ci < 20; ci++) {
            float wreg[25];
            const float* wp = wch + ci*28;
#pragma unroll
            for (int g = 0; g < 6; g++) {
                const float4 v = *(const float4*)(wp + 4*g);
                wreg[4*g+0] = v.x; wreg[4*g+1] = v.y;
                wreg[4*g+2] = v.z; wreg[4*g+3] = v.w;
            }
            wreg[24] = wp[24];
#pragma unroll
            for (int j = 0; j < 6; j++) {    // input rows 2py2..2py2+5, once
                float rr[12];
                const float* rp = &pool1[ci*144 + (2*py2 + j)*12]; // 16B-aligned
#pragma unroll
                for (int q = 0; q < 3; q++) {
                    const float4 v = *(const float4*)(rp + 4*q);
                    rr[4*q+0] = v.x; rr[4*q+1] = v.y;
                    rr[4*q+2] = v.z; rr[4*q+3] = v.w;
                }
                if (j <= 4) {                 // out row 2py2, tap ky=j
#pragma unroll
                    for (int kx = 0; kx < 5; kx++) {
                        const float wv = wreg[j*5 + kx];
#pragma unroll
                        for (int xo = 0; xo < 8; xo++)
                            acc2[xo] = fmaf(rr[xo+kx], wv, acc2[xo]);
                    }
                }
                if (j >= 1) {                 // out row 2py2+1, tap ky=j-1
#pragma unroll
                    for (int kx = 0; kx < 5; kx++) {
                        const float wv = wreg[(j-1)*5 + kx];
#pragma unroll
                        for (int xo = 0; xo < 8; xo++)
                            acc2[8+xo] = fmaf(rr[xo+kx], wv, acc2[8+xo]);
                    }
                }
            }
        }
        const float bias = b2s[c2];
#pragma unroll
        for (int px = 0; px < 4; px++) {
            float v = fmaxf(fmaxf(acc2[2*px], acc2[2*px+1]),
                            fmaxf(acc2[8+2*px], acc2[8+2*px+1]));
            pool2[c2*16 + py2*4 + px] = fmaxf(v + bias, 0.f);
        }
    }
    __syncthreads();

    // ---- fc: one wave per o-slice
    {
        const int wv = t >> 6, lane = t & 63;
        for (int o = wv; o < 50; o += 4) {
            float acc = 0.f;
#pragma unroll
            for (int r = 0; r < 13; r++) {
                const int k = r*64 + lane;
                if (k < 800) acc = fmaf(fcw[o*800 + k], pool2[k], acc);
            }
#pragma unroll
            for (int off = 32; off > 0; off >>= 1) acc += __shfl_xor(acc, off);
            if (lane == 0) hloc[o] = fmaxf(acc + fcb[o], 0.f);
        }
    }
    __syncthreads();
    if (t < 50) {
        const float v = hloc[t];
        hout[(size_t)n*50 + t] = v;
        hT[(size_t)t*4096 + n] = v;
    }
    if (t < 64) {
        float s = (t < 50) ? hloc[t]*hloc[t] : 0.f;
#pragma unroll
        for (int off = 32; off > 0; off >>= 1) s += __shfl_xor(s, off);
        if (t == 0) sqout[n] = s;
    }
}

// ============================================================
// Kernel 1b: S[d] = sum_n h[n][d]
// ============================================================
__global__ __launch_bounds__(256) void mil_colsum(
    const float* __restrict__ hT, float* __restrict__ S)
{
    __shared__ float red[4];
    const int d = blockIdx.x, t = threadIdx.x;
    float s = 0.f;
    for (int nn = t; nn < 4096; nn += 256) s += hT[(size_t)d*4096 + nn];
#pragma unroll
    for (int off = 32; off > 0; off >>= 1) s += __shfl_xor(s, off);
    if ((t & 63) == 0) red[t >> 6] = s;
    __syncthreads();
    if (t == 0) S[d] = red[0] + red[1] + red[2] + red[3];
}

// ============================================================
// Kernel 2: pairwise distances -> histogram buckets + bucket bytes.
// Per-pair LDS atomics (round-8 proven; ballot aggregation regressed).
// ============================================================
__global__ __launch_bounds__(256, 3) void mil_hist(
    const float* __restrict__ hT, const float* __restrict__ sq,
    unsigned int* __restrict__ hist, unsigned char* __restrict__ bytesA,
    const int wb)
{
    __shared__ __align__(16) float hiT[6400];   // [50][128]
    __shared__ __align__(16) float hjT[6400];
    __shared__ float sqi[128], sqj[128];
    __shared__ unsigned int lh[257];

    const int t = threadIdx.x;
    const int i0 = blockIdx.x * 128, j0 = blockIdx.y * 128;

    for (int idx = t; idx < 6400; idx += 256) {
        const int c = idx >> 7, l = idx & 127;
        hiT[idx] = hT[(size_t)c*4096 + i0 + l];
        hjT[idx] = hT[(size_t)c*4096 + j0 + l];
    }
    if (t < 128) { sqi[t] = sq[i0 + t]; sqj[t] = sq[j0 + t]; }
    for (int idx = t; idx < 257; idx += 256) lh[idx] = 0;
    __syncthreads();

    const int ti = t >> 4, tj = t & 15;
    float acc[8][8];
#pragma unroll
    for (int a = 0; a < 8; a++)
#pragma unroll
        for (int b = 0; b < 8; b++) acc[a][b] = 0.f;

    for (int c = 0; c < 50; c++) {
        const float4 a0 = *(const float4*)&hiT[c*128 + ti*8];
        const float4 a1 = *(const float4*)&hiT[c*128 + ti*8 + 4];
        const float4 b0 = *(const float4*)&hjT[c*128 + tj*8];
        const float4 b1 = *(const float4*)&hjT[c*128 + tj*8 + 4];
        const float aa[8] = {a0.x,a0.y,a0.z,a0.w,a1.x,a1.y,a1.z,a1.w};
        const float bb[8] = {b0.x,b0.y,b0.z,b0.w,b1.x,b1.y,b1.z,b1.w};
#pragma unroll
        for (int a = 0; a < 8; a++)
#pragma unroll
            for (int b = 0; b < 8; b++)
                acc[a][b] = fmaf(aa[a], bb[b], acc[a][b]);
    }

    unsigned int cnt0 = 0;
#pragma unroll
    for (int a = 0; a < 8; a++) {
        unsigned pk0 = 0, pk1 = 0;
#pragma unroll
        for (int b = 0; b < 8; b++) {
            const int gi = i0 + ti*8 + a, gj = j0 + tj*8 + b;
            int kbyte = 255;
            if (gi != gj) {
                const float d2 = sqi[ti*8+a] + sqj[tj*8+b] - 2.f*acc[a][b];
                const float d = sqrtf(fmaxf(d2, 0.f));
                int k = (int)floorf((d - 3.5f)*2.f) + 1;
                k = k < 0 ? 0 : (k > 256 ? 256 : k);
                if (k > 0   && d <  3.5f + 0.5f*(float)(k-1)) k--;
                if (k < 256 && d >= 3.5f + 0.5f*(float)k)     k++;
                if (k == 0) cnt0++;
                else atomicAdd(&lh[k], 1u);
                kbyte = k < 255 ? k : 255;
            }
            if (b < 4) pk0 |= (unsigned)kbyte << (8*b);
            else       pk1 |= (unsigned)kbyte << (8*(b-4));
        }
        if (wb) {
            const int gi = i0 + ti*8 + a;
            *(uint2*)&bytesA[(size_t)gi*4096 + j0 + tj*8] = make_uint2(pk0, pk1);
        }
    }
#pragma unroll
    for (int off = 32; off > 0; off >>= 1) cnt0 += __shfl_xor(cnt0, off);
    if ((t & 63) == 0 && cnt0) atomicAdd(&lh[0], cnt0);
    __syncthreads();
    for (int idx = t; idx < 257; idx += 256)
        if (lh[idx]) atomicAdd(&hist[idx], lh[idx]);
}

// ============================================================
// Kernel 3: prefix-scan -> kc, nnz, complement flag, byte-fallback flag
// ============================================================
__global__ void mil_scan(const unsigned int* __restrict__ hist, int* __restrict__ scal)
{
    if (threadIdx.x == 0) {
        unsigned long long cum = 0, nz = 0;
        int kc = -1;
        for (int k = 0; k < 256; k++) {
            cum += hist[k];
            if (kc < 0 && cum >= 410ull) { kc = k; nz = cum; }  // ceil(0.1*4096)
        }
        if (kc < 0) { kc = 0; nz = hist[0]; }
        scal[0] = kc;
        scal[1] = (int)nz;
        scal[2] = (nz * 2ull > 16773120ull) ? 1 : 0;   // complement if >half dense
        scal[3] = (kc >= 255) ? 1 : 0;                 // byte path ambiguous
    }
}

// ============================================================
// Kernel 4a: byte-driven aggregate (no gram recompute).
// ============================================================
__global__ __launch_bounds__(256) void mil_agg_b(
    const float* __restrict__ h, const unsigned char* __restrict__ bytesA,
    const int* __restrict__ scal, float* __restrict__ agg, float* __restrict__ deg)
{
    __shared__ __align__(16) unsigned char bL[64*528];
    __shared__ __align__(16) float hsub[4096];      // [jj][d], d padded to 64
    if (scal[3] != 0) return;                        // fallback kernel handles
    const int t = threadIdx.x;
    const int i0 = blockIdx.x * 64;
    const int jg = blockIdx.y * 512;
    const int kc = scal[0];
    const bool inv = (scal[2] != 0);

    for (int idx = t; idx < 2048; idx += 256) {
        const int r = idx >> 5, c = idx & 31;
        *(uint4*)&bL[r*528 + c*16] =
            *(const uint4*)&bytesA[(size_t)(i0 + r)*4096 + jg + c*16];
    }

    const int il = t >> 2, dq = t & 3;
    const int gi = i0 + il;
    float accum[16];
#pragma unroll
    for (int i = 0; i < 16; i++) accum[i] = 0.f;
    int degc = 0;

    for (int js = 0; js < 8; js++) {
        __syncthreads();
        for (int idx = t; idx < 4096; idx += 256) {
            const int jj = idx >> 6, d = idx & 63;
            hsub[idx] = (d < 50) ? h[(size_t)(jg + js*64 + jj)*50 + d] : 0.f;
        }
        __syncthreads();
        const unsigned char* brow = &bL[il*528 + js*64];
        const int jbase = jg + js*64;
        for (int jj = 0; jj < 64; jj++) {
            const bool e = (jbase + jj != gi) && ((brow[jj] <= kc) != inv);
            if (!__any(e)) continue;          // fast path: whole-wave skip
            const float m = e ? 1.f : 0.f;
            if (e && dq == 0) degc++;
#pragma unroll
            for (int q = 0; q < 4; q++) {
                const float4 hv = *(const float4*)&hsub[jj*64 + dq*16 + q*4];
                accum[q*4+0] = fmaf(m, hv.x, accum[q*4+0]);
                accum[q*4+1] = fmaf(m, hv.y, accum[q*4+1]);
                accum[q*4+2] = fmaf(m, hv.z, accum[q*4+2]);
                accum[q*4+3] = fmaf(m, hv.w, accum[q*4+3]);
            }
        }
    }

#pragma unroll
    for (int q = 0; q < 4; q++)
#pragma unroll
        for (int rr = 0; rr < 4; rr++) {
            const int d = dq*16 + q*4 + rr;
            if (d < 50 && accum[q*4+rr] != 0.f)
                atomicAdd(&agg[(size_t)gi*50 + d], accum[q*4+rr]);
        }
    if (dq == 0 && degc) atomicAdd(&deg[gi], (float)degc);
}

// ============================================================
// Kernel 4b: recompute-gram aggregate (fallback)
// ============================================================
__global__ __launch_bounds__(256, 3) void mil_agg_r(
    const float* __restrict__ h, const float* __restrict__ hT, const float* __restrict__ sq,
    const int* __restrict__ scal, float* __restrict__ agg, float* __restrict__ deg,
    const int mode)
{
    __shared__ __align__(16) float hiT[3200];       // [50][64]
    __shared__ __align__(16) float hjT[3200];
    __shared__ float sqi[64], sqj[64];
    __shared__ __align__(16) float hsub[4096];
    __shared__ __align__(16) unsigned char mk[4096];

    if (mode == 1 && scal[3] == 0) return;   // byte kernel handled it
    const int t = threadIdx.x;
    const int i0 = blockIdx.x * 64;
    const float thr = 3.5f + 0.5f * (float)scal[0];
    const bool inv = (scal[2] != 0);

    for (int idx = t; idx < 3200; idx += 256) {
        const int c = idx >> 6, l = idx & 63;
        hiT[idx] = hT[(size_t)c*4096 + i0 + l];
    }
    if (t < 64) sqi[t] = sq[i0 + t];

    const int ti = t >> 4, tj = t & 15;
    const int il = t >> 2, dq = t & 3;
    float accum[16];
#pragma unroll
    for (int i = 0; i < 16; i++) accum[i] = 0.f;
    int degc = 0;

    for (int js = 0; js < 8; js++) {
        const int j0 = blockIdx.y * 512 + js * 64;
        __syncthreads();
        for (int idx = t; idx < 3200; idx += 256) {
            const int c = idx >> 6, l = idx & 63;
            hjT[idx] = hT[(size_t)c*4096 + j0 + l];
        }
        for (int idx = t; idx < 4096; idx += 256) {
            const int jj = idx >> 6, d = idx & 63;
            hsub[idx] = (d < 50) ? h[(size_t)(j0 + jj)*50 + d] : 0.f;
        }
        if (t < 64) sqj[t] = sq[j0 + t];
        __syncthreads();

        float acc[4][4];
#pragma unroll
        for (int a = 0; a < 4; a++)
#pragma unroll
            for (int b = 0; b < 4; b++) acc[a][b] = 0.f;
        for (int c = 0; c < 50; c++) {
            const float4 av = *(const float4*)&hiT[c*64 + ti*4];
            const float4 bv = *(const float4*)&hjT[c*64 + tj*4];
            const float aa[4] = {av.x, av.y, av.z, av.w};
            const float bb[4] = {bv.x, bv.y, bv.z, bv.w};
#pragma unroll
            for (int a = 0; a < 4; a++)
#pragma unroll
                for (int b = 0; b < 4; b++)
                    acc[a][b] = fmaf(aa[a], bb[b], acc[a][b]);
        }

#pragma unroll
        for (int b = 0; b < 4; b++) {
            unsigned char ob[4];
#pragma unroll
            for (int a = 0; a < 4; a++) {
                const int gi = i0 + ti*4 + a, gj = j0 + tj*4 + b;
                const float d2 = sqi[ti*4+a] + sqj[tj*4+b] - 2.f*acc[a][b];
                const float dd = sqrtf(fmaxf(d2, 0.f));
                const bool edge = (dd < thr);
                ob[a] = (gi != gj && (edge != inv)) ? 1 : 0;
            }
            *(uchar4*)&mk[(tj*4+b)*64 + ti*4] = make_uchar4(ob[0], ob[1], ob[2], ob[3]);
        }
        __syncthreads();

        for (int jj = 0; jj < 64; jj++) {
            const bool e = (mk[jj*64 + il] != 0);
            if (!__any(e)) continue;
            const float m = e ? 1.f : 0.f;
            if (e && dq == 0) degc++;
#pragma unroll
            for (int q = 0; q < 4; q++) {
                const float4 hv = *(const float4*)&hsub[jj*64 + dq*16 + q*4];
                accum[q*4+0] = fmaf(m, hv.x, accum[q*4+0]);
                accum[q*4+1] = fmaf(m, hv.y, accum[q*4+1]);
                accum[q*4+2] = fmaf(m, hv.z, accum[q*4+2]);
                accum[q*4+3] = fmaf(m, hv.w, accum[q*4+3]);
            }
        }
    }

    const int node = i0 + il;
#pragma unroll
    for (int q = 0; q < 4; q++)
#pragma unroll
        for (int rr = 0; rr < 4; rr++) {
            const int d = dq*16 + q*4 + rr;
            if (d < 50 && accum[q*4+rr] != 0.f)
                atomicAdd(&agg[(size_t)node*50 + d], accum[q*4+rr]);
        }
    if (dq == 0 && degc) atomicAdd(&deg[node], (float)degc);
}

// ============================================================
// Kernel 5: Z = leaky(mean-agg@relW^T + relb + h@rootW^T); Xp += colsum(Z)
// ============================================================
__global__ __launch_bounds__(256) void mil_sage(
    const float* __restrict__ h, const float* __restrict__ agg, const float* __restrict__ deg,
    const float* __restrict__ S, const int* __restrict__ scal,
    const float* __restrict__ relw, const float* __restrict__ relb,
    const float* __restrict__ rootw, float* __restrict__ Xp)
{
    __shared__ float relT[2500];   // [c][d]
    __shared__ float rootT[2500];
    __shared__ float rb[50];
    __shared__ float hn[250], mn[250], zb[250];
    const int t = threadIdx.x;
    const int nb = blockIdx.x * 5;
    const bool inv = (scal[2] != 0);

    for (int idx = t; idx < 2500; idx += 256) {
        const int d = idx / 50, c = idx % 50;
        relT[c*50 + d]  = relw[idx];
        rootT[c*50 + d] = rootw[idx];
    }
    if (t < 50) rb[t] = relb[t];
    if (t < 250) {
        const int nl = t / 50, d = t % 50;
        const int node = nb + nl;
        if (node < 4096) {
            const float hv = h[(size_t)node*50 + d];
            float av = agg[(size_t)node*50 + d];
            float dg = deg[node];
            if (inv) { av = S[d] - hv - av; dg = 4095.f - dg; }
            hn[t] = hv;
            mn[t] = av / fmaxf(dg, 1.f);
        } else { hn[t] = 0.f; mn[t] = 0.f; }
    }
    __syncthreads();
    if (t < 250) {
        const int nl = t / 50, d = t % 50;
        float z = rb[d];
        for (int c = 0; c < 50; c++) {
            z = fmaf(mn[nl*50 + c], relT[c*50 + d], z);
            z = fmaf(hn[nl*50 + c], rootT[c*50 + d], z);
        }
        z = z > 0.f ? z : 0.01f * z;
        zb[t] = (nb + nl < 4096) ? z : 0.f;
    }
    __syncthreads();
    if (t < 50) {
        float s = 0.f;
#pragma unroll
        for (int nl = 0; nl < 5; nl++) s += zb[nl*50 + t];
        atomicAdd(&Xp[t], s);
    }
}

// ============================================================
// Kernel 6: pooled sage + lin1 + lin2 + softmax -> out[3] (f32)
// ============================================================
__global__ void mil_final(
    const float* __restrict__ Xp, const int* __restrict__ scal,
    const float* __restrict__ relw, const float* __restrict__ relb,
    const float* __restrict__ rootw,
    const float* __restrict__ l1w, const float* __restrict__ l1b,
    const float* __restrict__ l2w, const float* __restrict__ l2b,
    float* __restrict__ out)
{
    __shared__ float xp[50], x2[50], v1[25], v2[2];
    const int t = threadIdx.x;
    if (t < 50) xp[t] = Xp[t];
    __syncthreads();
    const float adjp = (float)scal[1];
    const float dmax = fmaxf(adjp, 1.f);
    if (t < 50) {
        float z = relb[t];
        for (int c = 0; c < 50; c++) {
            const float mnc = (adjp * xp[c]) / dmax;
            z = fmaf(mnc,   relw[t*50 + c], z);
            z = fmaf(xp[c], rootw[t*50 + c], z);
        }
        x2[t] = z > 0.f ? z : 0.01f*z;
    }
    __syncthreads();
    if (t < 25) {
        float v = l1b[t];
        for (int c = 0; c < 50; c++) v = fmaf(l1w[t*50 + c], x2[c], v);
        v1[t] = v > 0.f ? v : 0.01f*v;
    }
    __syncthreads();
    if (t < 2) {
        float v = l2b[t];
        for (int c = 0; c < 25; c++) v = fmaf(l2w[t*25 + c], v1[c], v);
        v2[t] = v > 0.f ? v : 0.01f*v;
    }
    __syncthreads();
    if (t == 0) {
        const float a = v2[0], b = v2[1];
        const float mx = fmaxf(a, b);
        const float e0 = expf(a - mx), e1 = expf(b - mx);
        const float s = e0 + e1;
        const float p0 = e0 / s, p1 = e1 / s;
        const float pm = fmaxf(p0, p1);
        const float am = (p1 > p0) ? 1.f : 0.f;
        const int nnz = scal[1];
        const float l1v = sqrtf((float)(16777216 - nnz)) / 16777216.f;
        out[0] = pm;
        out[1] = am;
        out[2] = l1v;
    }
}

// ============================================================
extern "C" void kernel_launch(void* const* d_in, const int* in_sizes, int n_in,
                              void* d_out, int out_size, void* d_ws, size_t ws_size,
                              hipStream_t stream)
{
    (void)in_sizes; (void)n_in; (void)out_size;
    const float* x     = (const float*)d_in[0];
    const float* w1    = (const float*)d_in[1];
    const float* b1    = (const float*)d_in[2];
    const float* w2    = (const float*)d_in[3];
    const float* b2    = (const float*)d_in[4];
    const float* fcw   = (const float*)d_in[5];
    const float* fcb   = (const float*)d_in[6];
    const float* relw  = (const float*)d_in[7];
    const float* relb  = (const float*)d_in[8];
    const float* rootw = (const float*)d_in[9];
    // d_in[10..14] (pool_*, mlp_*) are dead: softmax over a length-1 axis == 1
    const float* l1w   = (const float*)d_in[15];
    const float* l1b   = (const float*)d_in[16];
    const float* l2w   = (const float*)d_in[17];
    const float* l2b   = (const float*)d_in[18];

    char* ws = (char*)d_ws;
    float* agg = (float*)(ws + AGG_OFF);
    float* deg = (float*)(ws + DEG_OFF);
    float* Xp  = (float*)(ws + XP_OFF);
    unsigned int* hist = (unsigned int*)(ws + HIST_OFF);
    int* scal  = (int*)(ws + SCAL_OFF);
    float* S   = (float*)(ws + S_OFF);
    float* w2p = (float*)(ws + W2P_OFF);
    float* h   = (float*)(ws + H_OFF);
    float* hT  = (float*)(ws + HT_OFF);
    float* sq  = (float*)(ws + SQ_OFF);
    unsigned char* bytesA = (unsigned char*)(ws + BYTES_OFF);

    const int have_bytes = (ws_size >= WS_NEED) ? 1 : 0;  // constant per process

    mil_init<<<818, 256, 0, stream>>>((unsigned int*)d_ws);
    mil_wpad<<<110, 256, 0, stream>>>(w2, w2p);
    mil_cnn<<<4096, 256, 0, stream>>>(x, w1, b1, w2p, b2, fcw, fcb, h, hT, sq);
    mil_colsum<<<50, 256, 0, stream>>>(hT, S);
    mil_hist<<<dim3(32, 32), 256, 0, stream>>>(hT, sq, hist, bytesA, have_bytes);
    mil_scan<<<1, 64, 0, stream>>>(hist, scal);
    if (have_bytes) {
        mil_agg_b<<<dim3(64, 8), 256, 0, stream>>>(h, bytesA, scal, agg, deg);
        mil_agg_r<<<dim3(64, 8), 256, 0, stream>>>(h, hT, sq, scal, agg, deg, 1);
    } else {
        mil_agg_r<<<dim3(64, 8), 256, 0, stream>>>(h, hT, sq, scal, agg, deg, 0);
    }
    mil_sage<<<820, 256, 0, stream>>>(h, agg, deg, S, scal, relw, relb, rootw, Xp);
    mil_final<<<1, 64, 0, stream>>>(Xp, scal, relw, relb, rootw,
                                    l1w, l1b, l2w, l2b, (float*)d_out);
}